// Round 2
// baseline (312.987 us; speedup 1.0000x reference)
//
#include <hip/hip_runtime.h>

#define N_NODES 40000
#define M_PAD   40064   // 313 * 128
#define N_EDGES 320000
#define N_GRAPHS 64
#define IN_DIM 128
#define HID4 256
#define OUT_DIM 128
#define LN_EPS 1e-5f

typedef short  s16x8  __attribute__((ext_vector_type(8)));
typedef __bf16 bf16x8 __attribute__((ext_vector_type(8)));
typedef float  f32x4  __attribute__((ext_vector_type(4)));

__device__ __forceinline__ unsigned short f2b(float f) {
    unsigned int u = __builtin_bit_cast(unsigned int, f);
    u += 0x7fffu + ((u >> 16) & 1u);   // round-to-nearest-even
    return (unsigned short)(u >> 16);
}
__device__ __forceinline__ float b2f(unsigned short h) {
    unsigned int u = (unsigned int)h << 16;
    return __builtin_bit_cast(float, u);
}
__device__ __forceinline__ float lo2f(unsigned int u) { return b2f((unsigned short)u); }
__device__ __forceinline__ float hi2f(unsigned int u) { return b2f((unsigned short)(u >> 16)); }
__device__ __forceinline__ unsigned int packb(float x, float y) {
    return (unsigned int)f2b(x) | ((unsigned int)f2b(y) << 16);
}

// direct global->LDS 16B DMA; lds base wave-uniform, HW scatters lane*16
__device__ __forceinline__ void gll16(const unsigned short* g, short* lds_base) {
    __builtin_amdgcn_global_load_lds(
        (const __attribute__((address_space(1))) unsigned int*)g,
        (__attribute__((address_space(3))) unsigned int*)lds_base, 16, 0, 0);
}

// ---------------- fused prep: x->bf16 (vectorized), weights->bf16 transposed, edges ----

#define XN (N_NODES * IN_DIM)          // 5,120,000
#define XT (XN / 8)                    // 640,000 threads, 8 elems each
#define WN 229376                      // 32768*3 + 131072
#define PREP_TOT (XT + WN + N_EDGES)

__global__ void prep_all(const float* __restrict__ x, const float* __restrict__ W1,
                         const float* __restrict__ fc1, const float* __restrict__ W2,
                         const float* __restrict__ W3, const float* __restrict__ w,
                         const int* __restrict__ src, const int* __restrict__ dst,
                         unsigned short* __restrict__ xb, unsigned short* __restrict__ W1t,
                         unsigned short* __restrict__ fc1t, unsigned short* __restrict__ W2t,
                         unsigned short* __restrict__ W3t, float* __restrict__ ew,
                         int* __restrict__ cnt_out, int* __restrict__ cnt_in) {
    int idx = blockIdx.x * 256 + threadIdx.x;
    if (idx < XT) {
        const float4* xv = (const float4*)x;
        float4 u = xv[idx * 2], v = xv[idx * 2 + 1];
        uint4 o;
        o.x = packb(u.x, u.y); o.y = packb(u.z, u.w);
        o.z = packb(v.x, v.y); o.w = packb(v.z, v.w);
        ((uint4*)xb)[idx] = o;
        return;
    }
    int j = idx - XT;
    if (j < 32768) { int k = j >> 8, n = j & 255; W1t[n * 128 + k] = f2b(W1[j]); return; }
    j -= 32768;
    if (j < 32768) { int k = j >> 8, n = j & 255; fc1t[n * 128 + k] = f2b(fc1[j]); return; }
    j -= 32768;
    if (j < 131072) { int k = j >> 8, n = j & 255; W2t[n * 512 + k] = f2b(W2[j]); return; }
    j -= 131072;
    if (j < 32768) { int k = j >> 7, n = j & 127; W3t[n * 256 + k] = f2b(W3[j]); return; }
    j -= 32768;
    if (j < N_EDGES) {
        float4 v = ((const float4*)w)[j];
        ew[j] = fmaxf(fmaxf(v.x, v.y), fmaxf(v.z, v.w));
        atomicAdd(&cnt_out[src[j]], 1);
        atomicAdd(&cnt_in[dst[j]], 1);
    }
}

// stage 1: 40 blocks x 256 threads, block b sums cnt[b*1000 .. b*1000+999]
__global__ void scan_part(const int* __restrict__ cnt, int* __restrict__ partial) {
    int b = blockIdx.x;
    int s = 0;
    for (int i = threadIdx.x; i < 1000; i += 256) s += cnt[b * 1000 + i];
#pragma unroll
    for (int m = 1; m < 64; m <<= 1) s += __shfl_xor(s, m);
    __shared__ int wsm[4];
    if ((threadIdx.x & 63) == 0) wsm[threadIdx.x >> 6] = s;
    __syncthreads();
    if (threadIdx.x == 0) partial[b] = wsm[0] + wsm[1] + wsm[2] + wsm[3];
}

// stage 2: 40 blocks x 1024 threads; exclusive scan -> off ; also inv-sqrt degrees
__global__ void scan_final(const int* __restrict__ cnt_in, const int* __restrict__ cnt_out,
                           const int* __restrict__ partial, int* __restrict__ off,
                           float* __restrict__ out_inv, float* __restrict__ in_inv) {
    int b = blockIdx.x, tid = threadIdx.x;
    int lane = tid & 63, wv = tid >> 6;
    int pre = 0;
    for (int j = 0; j < b; ++j) pre += partial[j];
    int i = b * 1000 + tid;
    int v = (tid < 1000) ? cnt_in[i] : 0;
    int x = v;
#pragma unroll
    for (int ofs = 1; ofs < 64; ofs <<= 1) {
        int t = __shfl_up(x, ofs);
        if (lane >= ofs) x += t;
    }
    __shared__ int wsum[16];
    if (lane == 63) wsum[wv] = x;
    __syncthreads();
    if (wv == 0 && lane < 16) {
        int s = wsum[lane];
#pragma unroll
        for (int ofs = 1; ofs < 16; ofs <<= 1) {
            int t = __shfl_up(s, ofs);
            if (lane >= ofs) s += t;
        }
        wsum[lane] = s;
    }
    __syncthreads();
    int incl = pre + (wv > 0 ? wsum[wv - 1] : 0) + x;
    if (tid < 1000) {
        off[i] = incl - v;   // exclusive
        in_inv[i] = rsqrtf(fmaxf((float)v, 1.0f));
        out_inv[i] = rsqrtf(fmaxf((float)cnt_out[i], 1.0f));
    }
    if (b == 39 && tid == 999) off[N_NODES] = incl;
}

// ---- fused csr_fill + fc1 GEMM(+LN) hetero launch: blocks [0,625) csr, [625,938) fc1 ----
// csr: consumes cnt_in as countdown cursor; emits packed (src, w*out_inv[src], w, 0).
// fc1: 128x256 tile, K=128, per-block-complete rows -> LN in epilogue. Overlaps csr.

__global__ __launch_bounds__(512) void csr_fc1(
    const int* __restrict__ src, const int* __restrict__ dst,
    const float* __restrict__ ew, const float* __restrict__ out_inv,
    const int* __restrict__ off, int* __restrict__ cnt_in, int4* __restrict__ es,
    const unsigned short* __restrict__ A, const unsigned short* __restrict__ Bt,
    unsigned short* __restrict__ C,
    const float* __restrict__ gamma, const float* __restrict__ beta) {
    __shared__ short As[4096];   // [128][32]
    __shared__ short Bs[8192];   // [256][32]
    __shared__ float lns[128][4];
    __shared__ float lnq[128][4];
    if (blockIdx.x < 625) {
        int e = blockIdx.x * 512 + threadIdx.x;
        if (e >= N_EDGES) return;
        int d = dst[e];
        int slot = off[d] + atomicSub(&cnt_in[d], 1) - 1;
        int s = src[e];
        float wv = ew[e];
        es[slot] = make_int4(s, __float_as_int(wv * out_inv[s]), __float_as_int(wv), 0);
        return;
    }
    int m0 = (blockIdx.x - 625) * 128;
    int tid = threadIdx.x;
    int lane = tid & 63, wave = tid >> 6;      // 0..7
    int wm = (wave >> 2) * 64, wn = (wave & 3) * 64;
    int quad = lane >> 4, r16 = lane & 15;
    f32x4 acc[4][4] = {};
    int lrow = lane >> 2;
    int kc = (lane & 3) * 8;
    short* ldsA = As + wave * 512;
    short* ldsB = Bs + wave * 512;

    for (int k0 = 0; k0 < 128; k0 += 32) {
        int kk = k0 + kc;
        int rr = wave * 16 + lrow;  // 0..127
        gll16(A + (size_t)(m0 + rr) * 128 + kk, ldsA);
        gll16(Bt + (size_t)rr * 128 + kk, ldsB);
        gll16(Bt + (size_t)(128 + rr) * 128 + kk, ldsB + 4096);
        __syncthreads();
        s16x8 af[4], bfr[4];
#pragma unroll
        for (int i = 0; i < 4; ++i)
            af[i] = *(const s16x8*)(As + (wm + i * 16 + r16) * 32 + quad * 8);
#pragma unroll
        for (int j = 0; j < 4; ++j)
            bfr[j] = *(const s16x8*)(Bs + (wn + j * 16 + r16) * 32 + quad * 8);
#pragma unroll
        for (int i = 0; i < 4; ++i)
#pragma unroll
            for (int j = 0; j < 4; ++j)
                acc[i][j] = __builtin_amdgcn_mfma_f32_16x16x32_bf16(
                    __builtin_bit_cast(bf16x8, af[i]), __builtin_bit_cast(bf16x8, bfr[j]),
                    acc[i][j], 0, 0, 0);
        __syncthreads();
    }

    // LayerNorm(affine) + relu from fp32 accumulators
#pragma unroll
    for (int i = 0; i < 4; ++i)
#pragma unroll
        for (int r = 0; r < 4; ++r) {
            float s = 0.0f, q = 0.0f;
#pragma unroll
            for (int j = 0; j < 4; ++j) { float v = acc[i][j][r]; s += v; q += v * v; }
#pragma unroll
            for (int m = 1; m < 16; m <<= 1) { s += __shfl_xor(s, m); q += __shfl_xor(q, m); }
            if (r16 == 0) {
                int row = wm + i * 16 + quad * 4 + r;
                lns[row][wave & 3] = s;
                lnq[row][wave & 3] = q;
            }
        }
    __syncthreads();
#pragma unroll
    for (int i = 0; i < 4; ++i) {
#pragma unroll
        for (int r = 0; r < 4; ++r) {
            int row = wm + i * 16 + quad * 4 + r;
            float s = lns[row][0] + lns[row][1] + lns[row][2] + lns[row][3];
            float q = lnq[row][0] + lnq[row][1] + lnq[row][2] + lnq[row][3];
            float mu = s * (1.0f / HID4);
            float var = q * (1.0f / HID4) - mu * mu;
            float rs = rsqrtf(var + LN_EPS);
            int m = m0 + row;
#pragma unroll
            for (int j = 0; j < 4; ++j) {
                int col = wn + j * 16 + r16;
                float v = (acc[i][j][r] - mu) * rs * gamma[col] + beta[col];
                C[(size_t)m * 256 + col] = f2b(fmaxf(v, 0.0f));
            }
        }
    }
}

// ---------------- gather aggregation: 512-thread blocks, one node per wave, uint4 loads ----
// D=128: quad-wave per row (16 lanes x 16B = 256B), 4 edges per load instruction.
// D=256: half-wave per row (32 lanes x 16B = 512B), 2 edges per load instruction, unroll 2.

template <int RELU, int WSEL>
__device__ __forceinline__ void gather_wave_128(int n, int lane,
        const unsigned short* __restrict__ h, const int* __restrict__ off,
        const int4* __restrict__ eg, const float* __restrict__ scale,
        unsigned short* __restrict__ outb) {
    int b = off[n], e = off[n + 1];
    int quad = lane >> 4, ql = lane & 15;
    const uint4* hu = (const uint4*)h;   // row stride 16 (128 bf16)
    float a0 = 0.f, a1 = 0.f, a2 = 0.f, a3 = 0.f, a4 = 0.f, a5 = 0.f, a6 = 0.f, a7 = 0.f;
    for (int i = b; i < e; i += 4) {
        int idx = i + quad;
        int4 ee = eg[idx < e ? idx : b];
        float w = (idx < e) ? __int_as_float(WSEL ? ee.z : ee.y) : 0.0f;
        uint4 p = hu[(size_t)ee.x * 16 + ql];
        a0 += w * lo2f(p.x); a1 += w * hi2f(p.x);
        a2 += w * lo2f(p.y); a3 += w * hi2f(p.y);
        a4 += w * lo2f(p.z); a5 += w * hi2f(p.z);
        a6 += w * lo2f(p.w); a7 += w * hi2f(p.w);
    }
    a0 += __shfl_xor(a0, 16); a1 += __shfl_xor(a1, 16);
    a2 += __shfl_xor(a2, 16); a3 += __shfl_xor(a3, 16);
    a4 += __shfl_xor(a4, 16); a5 += __shfl_xor(a5, 16);
    a6 += __shfl_xor(a6, 16); a7 += __shfl_xor(a7, 16);
    a0 += __shfl_xor(a0, 32); a1 += __shfl_xor(a1, 32);
    a2 += __shfl_xor(a2, 32); a3 += __shfl_xor(a3, 32);
    a4 += __shfl_xor(a4, 32); a5 += __shfl_xor(a5, 32);
    a6 += __shfl_xor(a6, 32); a7 += __shfl_xor(a7, 32);
    float sc = scale[n];
    a0 *= sc; a1 *= sc; a2 *= sc; a3 *= sc; a4 *= sc; a5 *= sc; a6 *= sc; a7 *= sc;
    if (RELU) {
        a0 = fmaxf(a0, 0.f); a1 = fmaxf(a1, 0.f); a2 = fmaxf(a2, 0.f); a3 = fmaxf(a3, 0.f);
        a4 = fmaxf(a4, 0.f); a5 = fmaxf(a5, 0.f); a6 = fmaxf(a6, 0.f); a7 = fmaxf(a7, 0.f);
    }
    if (quad == 0) {
        uint4 o;
        o.x = packb(a0, a1); o.y = packb(a2, a3); o.z = packb(a4, a5); o.w = packb(a6, a7);
        ((uint4*)outb)[(size_t)n * 16 + ql] = o;
    }
}

template <int RELU, int WSEL>
__device__ __forceinline__ void gather_wave_256(int n, int lane,
        const unsigned short* __restrict__ h, const int* __restrict__ off,
        const int4* __restrict__ eg, const float* __restrict__ scale,
        unsigned short* __restrict__ outb) {
    int b = off[n], e = off[n + 1];
    int half = lane >> 5, cl = lane & 31;
    const uint4* hu = (const uint4*)h;   // row stride 32 (256 bf16)
    float a0 = 0.f, a1 = 0.f, a2 = 0.f, a3 = 0.f, a4 = 0.f, a5 = 0.f, a6 = 0.f, a7 = 0.f;
    int i = b;
    for (; i + 3 < e; i += 4) {
        int4 ea = eg[i + half], eb = eg[i + 2 + half];
        uint4 pa = hu[(size_t)ea.x * 32 + cl];
        uint4 pb = hu[(size_t)eb.x * 32 + cl];
        float wa = __int_as_float(WSEL ? ea.z : ea.y);
        float wb = __int_as_float(WSEL ? eb.z : eb.y);
        a0 += wa * lo2f(pa.x) + wb * lo2f(pb.x); a1 += wa * hi2f(pa.x) + wb * hi2f(pb.x);
        a2 += wa * lo2f(pa.y) + wb * lo2f(pb.y); a3 += wa * hi2f(pa.y) + wb * hi2f(pb.y);
        a4 += wa * lo2f(pa.z) + wb * lo2f(pb.z); a5 += wa * hi2f(pa.z) + wb * hi2f(pb.z);
        a6 += wa * lo2f(pa.w) + wb * lo2f(pb.w); a7 += wa * hi2f(pa.w) + wb * hi2f(pb.w);
    }
    for (; i < e; i += 2) {
        int idx = i + half;
        int4 ee = eg[idx < e ? idx : b];
        float w = (idx < e) ? __int_as_float(WSEL ? ee.z : ee.y) : 0.0f;
        uint4 p = hu[(size_t)ee.x * 32 + cl];
        a0 += w * lo2f(p.x); a1 += w * hi2f(p.x);
        a2 += w * lo2f(p.y); a3 += w * hi2f(p.y);
        a4 += w * lo2f(p.z); a5 += w * hi2f(p.z);
        a6 += w * lo2f(p.w); a7 += w * hi2f(p.w);
    }
    a0 += __shfl_xor(a0, 32); a1 += __shfl_xor(a1, 32);
    a2 += __shfl_xor(a2, 32); a3 += __shfl_xor(a3, 32);
    a4 += __shfl_xor(a4, 32); a5 += __shfl_xor(a5, 32);
    a6 += __shfl_xor(a6, 32); a7 += __shfl_xor(a7, 32);
    float sc = scale[n];
    a0 *= sc; a1 *= sc; a2 *= sc; a3 *= sc; a4 *= sc; a5 *= sc; a6 *= sc; a7 *= sc;
    if (RELU) {
        a0 = fmaxf(a0, 0.f); a1 = fmaxf(a1, 0.f); a2 = fmaxf(a2, 0.f); a3 = fmaxf(a3, 0.f);
        a4 = fmaxf(a4, 0.f); a5 = fmaxf(a5, 0.f); a6 = fmaxf(a6, 0.f); a7 = fmaxf(a7, 0.f);
    }
    if (half == 0) {
        uint4 o;
        o.x = packb(a0, a1); o.y = packb(a2, a3); o.z = packb(a4, a5); o.w = packb(a6, a7);
        ((uint4*)outb)[(size_t)n * 32 + cl] = o;
    }
}

template <int D, int RELU, int WSEL>
__global__ __launch_bounds__(512) void gather_nodes(
        const unsigned short* __restrict__ h, const int* __restrict__ off,
        const int4* __restrict__ eg, const float* __restrict__ scale,
        unsigned short* __restrict__ outb) {
    int wave = threadIdx.x >> 6, lane = threadIdx.x & 63;
    int n = blockIdx.x * 8 + wave;
    if (n >= N_NODES) return;
    if constexpr (D == 256)
        gather_wave_256<RELU, WSEL>(n, lane, h, off, eg, scale, outb);
    else
        gather_wave_128<RELU, WSEL>(n, lane, h, off, eg, scale, outb);
}

// ---------------- gather conv3 + fused readout (8 waves/block, 8-node run per wave) ------

#define G3_NPB 8

__global__ __launch_bounds__(512) void gather3_ro(
        const unsigned short* __restrict__ h, const int* __restrict__ off,
        const int4* __restrict__ eg, const float* __restrict__ scale,
        const int* __restrict__ gid, float* __restrict__ ro) {
    int wave = threadIdx.x >> 6, lane = threadIdx.x & 63;
    int quad = lane >> 4, ql = lane & 15;
    int n0 = (blockIdx.x * 8 + wave) * G3_NPB;
    if (n0 >= N_NODES) return;
    int n1 = n0 + G3_NPB;
    if (n1 > N_NODES) n1 = N_NODES;
    const uint4* hu = (const uint4*)h;   // row stride 16 (128 bf16)
    float r0 = 0.f, r1 = 0.f, r2 = 0.f, r3 = 0.f, r4 = 0.f, r5 = 0.f, r6 = 0.f, r7 = 0.f;
    int cur = gid[n0];
    for (int n = n0; n < n1; ++n) {
        int g = gid[n];
        if (g != cur) {
            if (quad == 0) {
                float* p = &ro[cur * OUT_DIM + ql * 8];
                atomicAdd(p + 0, r0); atomicAdd(p + 1, r1); atomicAdd(p + 2, r2);
                atomicAdd(p + 3, r3); atomicAdd(p + 4, r4); atomicAdd(p + 5, r5);
                atomicAdd(p + 6, r6); atomicAdd(p + 7, r7);
            }
            r0 = r1 = r2 = r3 = r4 = r5 = r6 = r7 = 0.f;
            cur = g;
        }
        int b = off[n], e = off[n + 1];
        float a0 = 0.f, a1 = 0.f, a2 = 0.f, a3 = 0.f, a4 = 0.f, a5 = 0.f, a6 = 0.f, a7 = 0.f;
        for (int i = b; i < e; i += 4) {
            int idx = i + quad;
            int4 ee = eg[idx < e ? idx : b];
            float w = (idx < e) ? __int_as_float(ee.z) : 0.0f;
            uint4 p = hu[(size_t)ee.x * 16 + ql];
            a0 += w * lo2f(p.x); a1 += w * hi2f(p.x);
            a2 += w * lo2f(p.y); a3 += w * hi2f(p.y);
            a4 += w * lo2f(p.z); a5 += w * hi2f(p.z);
            a6 += w * lo2f(p.w); a7 += w * hi2f(p.w);
        }
        a0 += __shfl_xor(a0, 16); a1 += __shfl_xor(a1, 16);
        a2 += __shfl_xor(a2, 16); a3 += __shfl_xor(a3, 16);
        a4 += __shfl_xor(a4, 16); a5 += __shfl_xor(a5, 16);
        a6 += __shfl_xor(a6, 16); a7 += __shfl_xor(a7, 16);
        a0 += __shfl_xor(a0, 32); a1 += __shfl_xor(a1, 32);
        a2 += __shfl_xor(a2, 32); a3 += __shfl_xor(a3, 32);
        a4 += __shfl_xor(a4, 32); a5 += __shfl_xor(a5, 32);
        a6 += __shfl_xor(a6, 32); a7 += __shfl_xor(a7, 32);
        float sc = scale[n];
        r0 += fmaxf(a0 * sc, 0.0f); r1 += fmaxf(a1 * sc, 0.0f);
        r2 += fmaxf(a2 * sc, 0.0f); r3 += fmaxf(a3 * sc, 0.0f);
        r4 += fmaxf(a4 * sc, 0.0f); r5 += fmaxf(a5 * sc, 0.0f);
        r6 += fmaxf(a6 * sc, 0.0f); r7 += fmaxf(a7 * sc, 0.0f);
    }
    if (quad == 0) {
        float* p = &ro[cur * OUT_DIM + ql * 8];
        atomicAdd(p + 0, r0); atomicAdd(p + 1, r1); atomicAdd(p + 2, r2);
        atomicAdd(p + 3, r3); atomicAdd(p + 4, r4); atomicAdd(p + 5, r5);
        atomicAdd(p + 6, r6); atomicAdd(p + 7, r7);
    }
}

// ---------------- MFMA bf16 GEMM core: 128x128 tile, BK=64, swizzled global_load_lds ------

__device__ __forceinline__ void gemm_core(short* As, short* Bs,
    const unsigned short* __restrict__ A, const unsigned short* __restrict__ A2,
    const unsigned short* __restrict__ Bt, unsigned short* __restrict__ C,
    const float* __restrict__ rowScaleC, int K1, int K2, int N,
    int relu, int scaleC, int m0, int n0) {
    int tid = threadIdx.x;
    int lane = tid & 63, wave = tid >> 6;
    int wm = (wave >> 1) * 64, wn = (wave & 1) * 64;
    int quad = lane >> 4, r16 = lane & 15;
    const int K = K1 + K2;
    f32x4 acc[4][4] = {};
    int srow = lane >> 3;                     // 0..7 (row within 8-row DMA group)
    int sk   = ((lane & 7) ^ srow) * 8;       // swizzled source k-chunk (elems)
    int xorc = r16 & 7;
    short* ldsA = As + wave * 2048;           // wave stages rows [wave*32, wave*32+32)
    short* ldsB = Bs + wave * 2048;

    for (int k0 = 0; k0 < K; k0 += 64) {
        int kk = k0 + sk;
#pragma unroll
        for (int h = 0; h < 4; ++h) {
            int r = wave * 32 + h * 8 + srow;
            const unsigned short* Ap = (k0 < K1)
                ? A  + (size_t)(m0 + r) * K1 + kk
                : A2 + (size_t)(m0 + r) * K2 + (kk - K1);
            gll16(Ap, ldsA + h * 512);
            gll16(Bt + (size_t)(n0 + r) * K + kk, ldsB + h * 512);
        }
        __syncthreads();
#pragma unroll
        for (int c = 0; c < 2; ++c) {
            s16x8 af[4], bfr[4];
            int pc = (((c * 4 + quad) ^ xorc) << 3);
#pragma unroll
            for (int i = 0; i < 4; ++i)
                af[i] = *(const s16x8*)(As + (wm + i * 16 + r16) * 64 + pc);
#pragma unroll
            for (int j = 0; j < 4; ++j)
                bfr[j] = *(const s16x8*)(Bs + (wn + j * 16 + r16) * 64 + pc);
#pragma unroll
            for (int i = 0; i < 4; ++i)
#pragma unroll
                for (int j = 0; j < 4; ++j)
                    acc[i][j] = __builtin_amdgcn_mfma_f32_16x16x32_bf16(
                        __builtin_bit_cast(bf16x8, af[i]), __builtin_bit_cast(bf16x8, bfr[j]),
                        acc[i][j], 0, 0, 0);
        }
        __syncthreads();
    }

#pragma unroll
    for (int i = 0; i < 4; ++i) {
        int mbase = m0 + wm + i * 16 + quad * 4;
#pragma unroll
        for (int r = 0; r < 4; ++r) {
            int m = mbase + r;
            float sc = scaleC ? rowScaleC[m] : 1.0f;
#pragma unroll
            for (int j = 0; j < 4; ++j) {
                float v = acc[i][j][r] * sc;
                if (relu) v = fmaxf(v, 0.0f);
                C[(size_t)m * N + n0 + wn + j * 16 + r16] = f2b(v);
            }
        }
    }
}

template <int RELU, int SCALE_C>
__global__ __launch_bounds__(256) void gemm_mfma(
    const unsigned short* __restrict__ A, const unsigned short* __restrict__ A2,
    const unsigned short* __restrict__ Bt, unsigned short* __restrict__ C,
    const float* __restrict__ rowScaleC, int K1, int K2, int N) {
    __shared__ short As[8192];
    __shared__ short Bs[8192];
    gemm_core(As, Bs, A, A2, Bt, C, rowScaleC, K1, K2, N, RELU, SCALE_C,
              blockIdx.x * 128, blockIdx.y * 128);
}

// -------- conv1 GEMM: 128x256 tile, 512 threads, K=128, relu ----

__global__ __launch_bounds__(512) void gemm_conv1(
    const unsigned short* __restrict__ A, const unsigned short* __restrict__ Bt,
    unsigned short* __restrict__ C) {
    __shared__ short As[4096];   // [128][32]
    __shared__ short Bs[8192];   // [256][32]
    int tid = threadIdx.x;
    int lane = tid & 63, wave = tid >> 6;      // 0..7
    int wm = (wave >> 2) * 64, wn = (wave & 3) * 64;
    int quad = lane >> 4, r16 = lane & 15;
    int m0 = blockIdx.x * 128;
    f32x4 acc[4][4] = {};
    int lrow = lane >> 2;
    int kc = (lane & 3) * 8;
    short* ldsA = As + wave * 512;
    short* ldsB = Bs + wave * 512;

    for (int k0 = 0; k0 < 128; k0 += 32) {
        int kk = k0 + kc;
        int rr = wave * 16 + lrow;  // 0..127
        gll16(A + (size_t)(m0 + rr) * 128 + kk, ldsA);
        gll16(Bt + (size_t)rr * 128 + kk, ldsB);
        gll16(Bt + (size_t)(128 + rr) * 128 + kk, ldsB + 4096);
        __syncthreads();
        s16x8 af[4], bfr[4];
#pragma unroll
        for (int i = 0; i < 4; ++i)
            af[i] = *(const s16x8*)(As + (wm + i * 16 + r16) * 32 + quad * 8);
#pragma unroll
        for (int j = 0; j < 4; ++j)
            bfr[j] = *(const s16x8*)(Bs + (wn + j * 16 + r16) * 32 + quad * 8);
#pragma unroll
        for (int i = 0; i < 4; ++i)
#pragma unroll
            for (int j = 0; j < 4; ++j)
                acc[i][j] = __builtin_amdgcn_mfma_f32_16x16x32_bf16(
                    __builtin_bit_cast(bf16x8, af[i]), __builtin_bit_cast(bf16x8, bfr[j]),
                    acc[i][j], 0, 0, 0);
        __syncthreads();
    }

#pragma unroll
    for (int i = 0; i < 4; ++i) {
        int mbase = m0 + wm + i * 16 + quad * 4;
#pragma unroll
        for (int r = 0; r < 4; ++r) {
            int m = mbase + r;
#pragma unroll
            for (int j = 0; j < 4; ++j)
                C[(size_t)m * 256 + wn + j * 16 + r16] = f2b(fmaxf(acc[i][j][r], 0.0f));
        }
    }
}

// ---------------- normalize ----------------

__global__ void normalize_out(const float* __restrict__ ro, float* __restrict__ out) {
    int g = blockIdx.x;
    int d = threadIdx.x;  // 128 threads = 2 waves
    float v = ro[g * OUT_DIM + d];
    float ss = v * v;
#pragma unroll
    for (int m = 1; m < 64; m <<= 1) ss += __shfl_xor(ss, m);
    __shared__ float s2[2];
    if ((d & 63) == 0) s2[d >> 6] = ss;
    __syncthreads();
    float tot = s2[0] + s2[1];
    float norm = fmaxf(sqrtf(tot), 1e-12f);
    out[g * OUT_DIM + d] = v / norm;
}

// ---------------- launch ----------------

extern "C" void kernel_launch(void* const* d_in, const int* in_sizes, int n_in,
                              void* d_out, int out_size, void* d_ws, size_t ws_size,
                              hipStream_t stream) {
    const float* x    = (const float*)d_in[0];
    const float* w    = (const float*)d_in[1];
    const float* W1   = (const float*)d_in[2];
    const float* fc1W = (const float*)d_in[3];
    const float* gam  = (const float*)d_in[4];
    const float* bet  = (const float*)d_in[5];
    const float* W2   = (const float*)d_in[6];
    const float* W3   = (const float*)d_in[7];
    const int* src = (const int*)d_in[8];
    const int* dst = (const int*)d_in[9];
    const int* gid = (const int*)d_in[10];
    float* out = (float*)d_out;

    float* ws = (float*)d_ws;
    float* out_inv = ws + 0;                                 // 40000
    float* in_inv  = ws + 40000;                             // 40000
    float* ew      = ws + 80000;                             // 320000
    int*   cnt_out = (int*)(ws + 400000);                    // 40000 (memset group start)
    int*   cnt_in  = (int*)(ws + 440000);                    // 40000 (memset group)
    float* ro      = ws + 480000;                            // 8192 (memset group end)
    unsigned short* W1t  = (unsigned short*)(ws + 488192);   // [256][128]
    unsigned short* fc1t = (unsigned short*)(ws + 504576);   // [256][128]
    unsigned short* W2t  = (unsigned short*)(ws + 520960);   // [256][512]
    unsigned short* W3t  = (unsigned short*)(ws + 586496);   // [128][256]
    int*   partial = (int*)(ws + 602880);                    // 40
    int*   off     = (int*)(ws + 602920);                    // 40001 ints -> ends 642921
    int4*  es      = (int4*)(ws + 642924);                   // 320000 int4 (16B-aligned)
    unsigned short* xb    = (unsigned short*)(ws + 1923000); // [M_PAD][128] ; later Q3b
    unsigned short* Q3b   = xb;
    unsigned short* agg1b = (unsigned short*)(ws + 4487100); // [M_PAD][128..256] ; later x2b
    unsigned short* x2b   = agg1b;
    unsigned short* x1b   = (unsigned short*)(ws + 9615300); // [M_PAD][256]
    unsigned short* f1b   = (unsigned short*)(ws + 14743500);// [M_PAD][256]
    unsigned short* P2b   = (unsigned short*)(ws + 19871700);// [M_PAD][256]

    // one memset covers cnt_out | cnt_in | ro (contiguous)
    hipMemsetAsync(cnt_out, 0, (2 * 40000 + N_GRAPHS * OUT_DIM) * sizeof(float), stream);

    // fused conversions + edge weights + degree histograms
    prep_all<<<(PREP_TOT + 255) / 256, 256, 0, stream>>>(x, W1, fc1W, W2, W3, w, src, dst,
                                                         xb, W1t, fc1t, W2t, W3t, ew,
                                                         cnt_out, cnt_in);
    scan_part<<<40, 256, 0, stream>>>(cnt_in, partial);
    scan_final<<<40, 1024, 0, stream>>>(cnt_in, cnt_out, partial, off, out_inv, in_inv);

    // fused: csr_fill (625 blocks) + fc1 GEMM+LN (313 blocks) — independent work overlapped
    csr_fc1<<<625 + 313, 512, 0, stream>>>(src, dst, ew, out_inv, off, cnt_in, es,
                                           xb, fc1t, f1b, gam, bet);

    // conv1 gather (8 waves/block, 1 node/wave), then conv1 GEMM
    gather_nodes<IN_DIM, 0, 0><<<5000, 512, 0, stream>>>(xb, off, es, in_inv, agg1b);
    gemm_conv1<<<313, 512, 0, stream>>>(agg1b, W1t, x1b);

    // conv2
    {
        dim3 grid(M_PAD / 128, HID4 / 128);
        gemm_mfma<0, 1><<<grid, 256, 0, stream>>>(x1b, f1b, W2t, P2b, out_inv,
                                                  HID4, HID4, HID4);
    }
    gather_nodes<HID4, 1, 1><<<5000, 512, 0, stream>>>(P2b, off, es, in_inv, x2b);

    // conv3
    {
        dim3 grid(M_PAD / 128, OUT_DIM / 128);
        gemm_mfma<0, 1><<<grid, 256, 0, stream>>>(x2b, nullptr, W3t, Q3b, out_inv,
                                                  HID4, 0, OUT_DIM);
    }
    // conv3 gather fused with readout (x3 never materialized)
    gather3_ro<<<625, 512, 0, stream>>>(Q3b, off, es, in_inv, gid, ro);
    normalize_out<<<N_GRAPHS, 128, 0, stream>>>(ro, out);
}

// Round 3
// 291.727 us; speedup vs baseline: 1.0729x; 1.0729x over previous
//
#include <hip/hip_runtime.h>

#define N_NODES 40000
#define M_PAD   40064   // 313 * 128
#define N_EDGES 320000
#define N_GRAPHS 64
#define IN_DIM 128
#define HID4 256
#define OUT_DIM 128
#define LN_EPS 1e-5f

typedef short  s16x8  __attribute__((ext_vector_type(8)));
typedef __bf16 bf16x8 __attribute__((ext_vector_type(8)));
typedef float  f32x4  __attribute__((ext_vector_type(4)));

__device__ __forceinline__ unsigned short f2b(float f) {
    unsigned int u = __builtin_bit_cast(unsigned int, f);
    u += 0x7fffu + ((u >> 16) & 1u);   // round-to-nearest-even
    return (unsigned short)(u >> 16);
}
__device__ __forceinline__ float b2f(unsigned short h) {
    unsigned int u = (unsigned int)h << 16;
    return __builtin_bit_cast(float, u);
}
__device__ __forceinline__ float lo2f(unsigned int u) { return b2f((unsigned short)u); }
__device__ __forceinline__ float hi2f(unsigned int u) { return b2f((unsigned short)(u >> 16)); }
__device__ __forceinline__ unsigned int packb(float x, float y) {
    return (unsigned int)f2b(x) | ((unsigned int)f2b(y) << 16);
}

// direct global->LDS 16B DMA; lds base wave-uniform, HW scatters lane*16
__device__ __forceinline__ void gll16(const unsigned short* g, short* lds_base) {
    __builtin_amdgcn_global_load_lds(
        (const __attribute__((address_space(1))) unsigned int*)g,
        (__attribute__((address_space(3))) unsigned int*)lds_base, 16, 0, 0);
}

// ---------------- fused prep: x->bf16 (vectorized), weights->bf16 transposed, edges ----

#define XN (N_NODES * IN_DIM)          // 5,120,000
#define XT (XN / 8)                    // 640,000 threads, 8 elems each
#define WN 229376                      // 32768*3 + 131072
#define PREP_TOT (XT + WN + N_EDGES)

__global__ void prep_all(const float* __restrict__ x, const float* __restrict__ W1,
                         const float* __restrict__ fc1, const float* __restrict__ W2,
                         const float* __restrict__ W3, const float* __restrict__ w,
                         const int* __restrict__ src, const int* __restrict__ dst,
                         unsigned short* __restrict__ xb, unsigned short* __restrict__ W1t,
                         unsigned short* __restrict__ fc1t, unsigned short* __restrict__ W2t,
                         unsigned short* __restrict__ W3t, float* __restrict__ ew,
                         int* __restrict__ cnt_out, int* __restrict__ cnt_in) {
    int idx = blockIdx.x * 256 + threadIdx.x;
    if (idx < XT) {
        const float4* xv = (const float4*)x;
        float4 u = xv[idx * 2], v = xv[idx * 2 + 1];
        uint4 o;
        o.x = packb(u.x, u.y); o.y = packb(u.z, u.w);
        o.z = packb(v.x, v.y); o.w = packb(v.z, v.w);
        ((uint4*)xb)[idx] = o;
        return;
    }
    int j = idx - XT;
    if (j < 32768) { int k = j >> 8, n = j & 255; W1t[n * 128 + k] = f2b(W1[j]); return; }
    j -= 32768;
    if (j < 32768) { int k = j >> 8, n = j & 255; fc1t[n * 128 + k] = f2b(fc1[j]); return; }
    j -= 32768;
    if (j < 131072) { int k = j >> 8, n = j & 255; W2t[n * 512 + k] = f2b(W2[j]); return; }
    j -= 131072;
    if (j < 32768) { int k = j >> 7, n = j & 127; W3t[n * 256 + k] = f2b(W3[j]); return; }
    j -= 32768;
    if (j < N_EDGES) {
        float4 v = ((const float4*)w)[j];
        ew[j] = fmaxf(fmaxf(v.x, v.y), fmaxf(v.z, v.w));
        atomicAdd(&cnt_out[src[j]], 1);
        atomicAdd(&cnt_in[dst[j]], 1);
    }
}

// stage 1: 40 blocks x 256 threads, block b sums cnt[b*1000 .. b*1000+999]
__global__ void scan_part(const int* __restrict__ cnt, int* __restrict__ partial) {
    int b = blockIdx.x;
    int s = 0;
    for (int i = threadIdx.x; i < 1000; i += 256) s += cnt[b * 1000 + i];
#pragma unroll
    for (int m = 1; m < 64; m <<= 1) s += __shfl_xor(s, m);
    __shared__ int wsm[4];
    if ((threadIdx.x & 63) == 0) wsm[threadIdx.x >> 6] = s;
    __syncthreads();
    if (threadIdx.x == 0) partial[b] = wsm[0] + wsm[1] + wsm[2] + wsm[3];
}

// stage 2: 40 blocks x 1024 threads; exclusive scan -> off ; also inv-sqrt degrees
__global__ void scan_final(const int* __restrict__ cnt_in, const int* __restrict__ cnt_out,
                           const int* __restrict__ partial, int* __restrict__ off,
                           float* __restrict__ out_inv, float* __restrict__ in_inv) {
    int b = blockIdx.x, tid = threadIdx.x;
    int lane = tid & 63, wv = tid >> 6;
    int pre = 0;
    for (int j = 0; j < b; ++j) pre += partial[j];
    int i = b * 1000 + tid;
    int v = (tid < 1000) ? cnt_in[i] : 0;
    int x = v;
#pragma unroll
    for (int ofs = 1; ofs < 64; ofs <<= 1) {
        int t = __shfl_up(x, ofs);
        if (lane >= ofs) x += t;
    }
    __shared__ int wsum[16];
    if (lane == 63) wsum[wv] = x;
    __syncthreads();
    if (wv == 0 && lane < 16) {
        int s = wsum[lane];
#pragma unroll
        for (int ofs = 1; ofs < 16; ofs <<= 1) {
            int t = __shfl_up(s, ofs);
            if (lane >= ofs) s += t;
        }
        wsum[lane] = s;
    }
    __syncthreads();
    int incl = pre + (wv > 0 ? wsum[wv - 1] : 0) + x;
    if (tid < 1000) {
        off[i] = incl - v;   // exclusive
        in_inv[i] = rsqrtf(fmaxf((float)v, 1.0f));
        out_inv[i] = rsqrtf(fmaxf((float)cnt_out[i], 1.0f));
    }
    if (b == 39 && tid == 999) off[N_NODES] = incl;
}

// ---- fused csr_fill + fc1 GEMM(+LN) hetero launch: blocks [0,625) csr, [625,938) fc1 ----

__global__ __launch_bounds__(512) void csr_fc1(
    const int* __restrict__ src, const int* __restrict__ dst,
    const float* __restrict__ ew, const float* __restrict__ out_inv,
    const int* __restrict__ off, int* __restrict__ cnt_in, int4* __restrict__ es,
    const unsigned short* __restrict__ A, const unsigned short* __restrict__ Bt,
    unsigned short* __restrict__ C,
    const float* __restrict__ gamma, const float* __restrict__ beta) {
    __shared__ short As[4096];   // [128][32]
    __shared__ short Bs[8192];   // [256][32]
    __shared__ float lns[128][4];
    __shared__ float lnq[128][4];
    if (blockIdx.x < 625) {
        int e = blockIdx.x * 512 + threadIdx.x;
        if (e >= N_EDGES) return;
        int d = dst[e];
        int slot = off[d] + atomicSub(&cnt_in[d], 1) - 1;
        int s = src[e];
        float wv = ew[e];
        es[slot] = make_int4(s, __float_as_int(wv * out_inv[s]), __float_as_int(wv), 0);
        return;
    }
    int m0 = (blockIdx.x - 625) * 128;
    int tid = threadIdx.x;
    int lane = tid & 63, wave = tid >> 6;      // 0..7
    int wm = (wave >> 2) * 64, wn = (wave & 3) * 64;
    int quad = lane >> 4, r16 = lane & 15;
    f32x4 acc[4][4] = {};
    int lrow = lane >> 2;
    int kc = (lane & 3) * 8;
    short* ldsA = As + wave * 512;
    short* ldsB = Bs + wave * 512;

    for (int k0 = 0; k0 < 128; k0 += 32) {
        int kk = k0 + kc;
        int rr = wave * 16 + lrow;  // 0..127
        gll16(A + (size_t)(m0 + rr) * 128 + kk, ldsA);
        gll16(Bt + (size_t)rr * 128 + kk, ldsB);
        gll16(Bt + (size_t)(128 + rr) * 128 + kk, ldsB + 4096);
        __syncthreads();
        s16x8 af[4], bfr[4];
#pragma unroll
        for (int i = 0; i < 4; ++i)
            af[i] = *(const s16x8*)(As + (wm + i * 16 + r16) * 32 + quad * 8);
#pragma unroll
        for (int j = 0; j < 4; ++j)
            bfr[j] = *(const s16x8*)(Bs + (wn + j * 16 + r16) * 32 + quad * 8);
#pragma unroll
        for (int i = 0; i < 4; ++i)
#pragma unroll
            for (int j = 0; j < 4; ++j)
                acc[i][j] = __builtin_amdgcn_mfma_f32_16x16x32_bf16(
                    __builtin_bit_cast(bf16x8, af[i]), __builtin_bit_cast(bf16x8, bfr[j]),
                    acc[i][j], 0, 0, 0);
        __syncthreads();
    }

    // LayerNorm(affine) + relu from fp32 accumulators
#pragma unroll
    for (int i = 0; i < 4; ++i)
#pragma unroll
        for (int r = 0; r < 4; ++r) {
            float s = 0.0f, q = 0.0f;
#pragma unroll
            for (int j = 0; j < 4; ++j) { float v = acc[i][j][r]; s += v; q += v * v; }
#pragma unroll
            for (int m = 1; m < 16; m <<= 1) { s += __shfl_xor(s, m); q += __shfl_xor(q, m); }
            if (r16 == 0) {
                int row = wm + i * 16 + quad * 4 + r;
                lns[row][wave & 3] = s;
                lnq[row][wave & 3] = q;
            }
        }
    __syncthreads();
#pragma unroll
    for (int i = 0; i < 4; ++i) {
#pragma unroll
        for (int r = 0; r < 4; ++r) {
            int row = wm + i * 16 + quad * 4 + r;
            float s = lns[row][0] + lns[row][1] + lns[row][2] + lns[row][3];
            float q = lnq[row][0] + lnq[row][1] + lnq[row][2] + lnq[row][3];
            float mu = s * (1.0f / HID4);
            float var = q * (1.0f / HID4) - mu * mu;
            float rs = rsqrtf(var + LN_EPS);
            int m = m0 + row;
#pragma unroll
            for (int j = 0; j < 4; ++j) {
                int col = wn + j * 16 + r16;
                float v = (acc[i][j][r] - mu) * rs * gamma[col] + beta[col];
                C[(size_t)m * 256 + col] = f2b(fmaxf(v, 0.0f));
            }
        }
    }
}

// ---------------- gather aggregation: 512-thread blocks (8 waves), one node per wave ----
// Half-split: lanes 0-31 even edges, lanes 32-63 odd edges; 4-deep unrolled main loop
// keeps 4 independent row loads in flight per lane (latency-bound regime, MLP is king).

template <int RELU, int WSEL>
__device__ __forceinline__ void gather_wave_128(int n, int lane,
        const unsigned short* __restrict__ h, const int* __restrict__ off,
        const int4* __restrict__ eg, const float* __restrict__ scale,
        unsigned short* __restrict__ outb) {
    int b = off[n], e = off[n + 1];
    int half = lane >> 5, cl = lane & 31;
    const uint2* hu = (const uint2*)h;   // row stride 32 (128 bf16)
    float a0 = 0.f, a1 = 0.f, a2 = 0.f, a3 = 0.f;
    int i = b;
    for (; i + 7 < e; i += 8) {
        int4 ea = eg[i + half],     eb = eg[i + 2 + half];
        int4 ec = eg[i + 4 + half], ed = eg[i + 6 + half];
        uint2 pa = hu[(size_t)ea.x * 32 + cl];
        uint2 pb = hu[(size_t)eb.x * 32 + cl];
        uint2 pc = hu[(size_t)ec.x * 32 + cl];
        uint2 pd = hu[(size_t)ed.x * 32 + cl];
        float wa = __int_as_float(WSEL ? ea.z : ea.y);
        float wb = __int_as_float(WSEL ? eb.z : eb.y);
        float wc = __int_as_float(WSEL ? ec.z : ec.y);
        float wd = __int_as_float(WSEL ? ed.z : ed.y);
        a0 += wa * lo2f(pa.x) + wb * lo2f(pb.x) + wc * lo2f(pc.x) + wd * lo2f(pd.x);
        a1 += wa * hi2f(pa.x) + wb * hi2f(pb.x) + wc * hi2f(pc.x) + wd * hi2f(pd.x);
        a2 += wa * lo2f(pa.y) + wb * lo2f(pb.y) + wc * lo2f(pc.y) + wd * lo2f(pd.y);
        a3 += wa * hi2f(pa.y) + wb * hi2f(pb.y) + wc * hi2f(pc.y) + wd * hi2f(pd.y);
    }
    for (; i + 3 < e; i += 4) {
        int4 ea = eg[i + half], eb = eg[i + 2 + half];
        uint2 pa = hu[(size_t)ea.x * 32 + cl];
        uint2 pb = hu[(size_t)eb.x * 32 + cl];
        float wa = __int_as_float(WSEL ? ea.z : ea.y);
        float wb = __int_as_float(WSEL ? eb.z : eb.y);
        a0 += wa * lo2f(pa.x) + wb * lo2f(pb.x);
        a1 += wa * hi2f(pa.x) + wb * hi2f(pb.x);
        a2 += wa * lo2f(pa.y) + wb * lo2f(pb.y);
        a3 += wa * hi2f(pa.y) + wb * hi2f(pb.y);
    }
    for (; i < e; i += 2) {
        int idx = i + half;
        int4 ee = eg[idx < e ? idx : i];
        float w = (idx < e) ? __int_as_float(WSEL ? ee.z : ee.y) : 0.0f;
        uint2 p = hu[(size_t)ee.x * 32 + cl];
        a0 += w * lo2f(p.x); a1 += w * hi2f(p.x);
        a2 += w * lo2f(p.y); a3 += w * hi2f(p.y);
    }
    a0 += __shfl_xor(a0, 32); a1 += __shfl_xor(a1, 32);
    a2 += __shfl_xor(a2, 32); a3 += __shfl_xor(a3, 32);
    float sc = scale[n];
    a0 *= sc; a1 *= sc; a2 *= sc; a3 *= sc;
    if (RELU) {
        a0 = fmaxf(a0, 0.f); a1 = fmaxf(a1, 0.f);
        a2 = fmaxf(a2, 0.f); a3 = fmaxf(a3, 0.f);
    }
    if (half == 0) {
        uint2 o; o.x = packb(a0, a1); o.y = packb(a2, a3);
        ((uint2*)outb)[(size_t)n * 32 + cl] = o;
    }
}

template <int RELU, int WSEL>
__device__ __forceinline__ void gather_wave_256(int n, int lane,
        const unsigned short* __restrict__ h, const int* __restrict__ off,
        const int4* __restrict__ eg, const float* __restrict__ scale,
        unsigned short* __restrict__ outb) {
    int b = off[n], e = off[n + 1];
    int half = lane >> 5, cl = lane & 31;
    const uint4* hu = (const uint4*)h;   // row stride 32 (256 bf16)
    float a0 = 0.f, a1 = 0.f, a2 = 0.f, a3 = 0.f, a4 = 0.f, a5 = 0.f, a6 = 0.f, a7 = 0.f;
    int i = b;
    for (; i + 7 < e; i += 8) {
        int4 ea = eg[i + half],     eb = eg[i + 2 + half];
        int4 ec = eg[i + 4 + half], ed = eg[i + 6 + half];
        uint4 pa = hu[(size_t)ea.x * 32 + cl];
        uint4 pb = hu[(size_t)eb.x * 32 + cl];
        uint4 pc = hu[(size_t)ec.x * 32 + cl];
        uint4 pd = hu[(size_t)ed.x * 32 + cl];
        float wa = __int_as_float(WSEL ? ea.z : ea.y);
        float wb = __int_as_float(WSEL ? eb.z : eb.y);
        float wc = __int_as_float(WSEL ? ec.z : ec.y);
        float wd = __int_as_float(WSEL ? ed.z : ed.y);
        a0 += wa * lo2f(pa.x) + wb * lo2f(pb.x) + wc * lo2f(pc.x) + wd * lo2f(pd.x);
        a1 += wa * hi2f(pa.x) + wb * hi2f(pb.x) + wc * hi2f(pc.x) + wd * hi2f(pd.x);
        a2 += wa * lo2f(pa.y) + wb * lo2f(pb.y) + wc * lo2f(pc.y) + wd * lo2f(pd.y);
        a3 += wa * hi2f(pa.y) + wb * hi2f(pb.y) + wc * hi2f(pc.y) + wd * hi2f(pd.y);
        a4 += wa * lo2f(pa.z) + wb * lo2f(pb.z) + wc * lo2f(pc.z) + wd * lo2f(pd.z);
        a5 += wa * hi2f(pa.z) + wb * hi2f(pb.z) + wc * hi2f(pc.z) + wd * hi2f(pd.z);
        a6 += wa * lo2f(pa.w) + wb * lo2f(pb.w) + wc * lo2f(pc.w) + wd * lo2f(pd.w);
        a7 += wa * hi2f(pa.w) + wb * hi2f(pb.w) + wc * hi2f(pc.w) + wd * hi2f(pd.w);
    }
    for (; i + 3 < e; i += 4) {
        int4 ea = eg[i + half], eb = eg[i + 2 + half];
        uint4 pa = hu[(size_t)ea.x * 32 + cl];
        uint4 pb = hu[(size_t)eb.x * 32 + cl];
        float wa = __int_as_float(WSEL ? ea.z : ea.y);
        float wb = __int_as_float(WSEL ? eb.z : eb.y);
        a0 += wa * lo2f(pa.x) + wb * lo2f(pb.x); a1 += wa * hi2f(pa.x) + wb * hi2f(pb.x);
        a2 += wa * lo2f(pa.y) + wb * lo2f(pb.y); a3 += wa * hi2f(pa.y) + wb * hi2f(pb.y);
        a4 += wa * lo2f(pa.z) + wb * lo2f(pb.z); a5 += wa * hi2f(pa.z) + wb * hi2f(pb.z);
        a6 += wa * lo2f(pa.w) + wb * lo2f(pb.w); a7 += wa * hi2f(pa.w) + wb * hi2f(pb.w);
    }
    for (; i < e; i += 2) {
        int idx = i + half;
        int4 ee = eg[idx < e ? idx : i];
        float w = (idx < e) ? __int_as_float(WSEL ? ee.z : ee.y) : 0.0f;
        uint4 p = hu[(size_t)ee.x * 32 + cl];
        a0 += w * lo2f(p.x); a1 += w * hi2f(p.x);
        a2 += w * lo2f(p.y); a3 += w * hi2f(p.y);
        a4 += w * lo2f(p.z); a5 += w * hi2f(p.z);
        a6 += w * lo2f(p.w); a7 += w * hi2f(p.w);
    }
    a0 += __shfl_xor(a0, 32); a1 += __shfl_xor(a1, 32);
    a2 += __shfl_xor(a2, 32); a3 += __shfl_xor(a3, 32);
    a4 += __shfl_xor(a4, 32); a5 += __shfl_xor(a5, 32);
    a6 += __shfl_xor(a6, 32); a7 += __shfl_xor(a7, 32);
    float sc = scale[n];
    a0 *= sc; a1 *= sc; a2 *= sc; a3 *= sc; a4 *= sc; a5 *= sc; a6 *= sc; a7 *= sc;
    if (RELU) {
        a0 = fmaxf(a0, 0.f); a1 = fmaxf(a1, 0.f); a2 = fmaxf(a2, 0.f); a3 = fmaxf(a3, 0.f);
        a4 = fmaxf(a4, 0.f); a5 = fmaxf(a5, 0.f); a6 = fmaxf(a6, 0.f); a7 = fmaxf(a7, 0.f);
    }
    if (half == 0) {
        uint4 o;
        o.x = packb(a0, a1); o.y = packb(a2, a3); o.z = packb(a4, a5); o.w = packb(a6, a7);
        ((uint4*)outb)[(size_t)n * 32 + cl] = o;
    }
}

template <int D, int RELU, int WSEL>
__global__ __launch_bounds__(512) void gather_nodes(
        const unsigned short* __restrict__ h, const int* __restrict__ off,
        const int4* __restrict__ eg, const float* __restrict__ scale,
        unsigned short* __restrict__ outb) {
    int wave = threadIdx.x >> 6, lane = threadIdx.x & 63;
    int n = blockIdx.x * 8 + wave;
    if (n >= N_NODES) return;
    if constexpr (D == 256)
        gather_wave_256<RELU, WSEL>(n, lane, h, off, eg, scale, outb);
    else
        gather_wave_128<RELU, WSEL>(n, lane, h, off, eg, scale, outb);
}

// ---------------- gather conv3 + fused readout (8 waves/block, 8-node run per wave) ------

#define G3_NPB 8

__global__ __launch_bounds__(512) void gather3_ro(
        const unsigned short* __restrict__ h, const int* __restrict__ off,
        const int4* __restrict__ eg, const float* __restrict__ scale,
        const int* __restrict__ gid, float* __restrict__ ro) {
    int wave = threadIdx.x >> 6, lane = threadIdx.x & 63;
    int half = lane >> 5, cl = lane & 31;   // lane covers cols 4cl..4cl+3 (half-split edges)
    int n0 = (blockIdx.x * 8 + wave) * G3_NPB;
    if (n0 >= N_NODES) return;
    int n1 = n0 + G3_NPB;
    if (n1 > N_NODES) n1 = N_NODES;
    const uint2* hu = (const uint2*)h;   // row stride 32 (128 bf16)
    float r0 = 0.f, r1 = 0.f, r2 = 0.f, r3 = 0.f;
    int cur = gid[n0];
    for (int n = n0; n < n1; ++n) {
        int g = gid[n];
        if (g != cur) {
            atomicAdd(&ro[cur * OUT_DIM + 4 * cl + 2 * half], half ? r2 : r0);
            atomicAdd(&ro[cur * OUT_DIM + 4 * cl + 2 * half + 1], half ? r3 : r1);
            r0 = r1 = r2 = r3 = 0.f;
            cur = g;
        }
        int b = off[n], e = off[n + 1];
        float a0 = 0.f, a1 = 0.f, a2 = 0.f, a3 = 0.f;
        int i = b;
        for (; i + 7 < e; i += 8) {
            int4 ea = eg[i + half],     eb = eg[i + 2 + half];
            int4 ec = eg[i + 4 + half], ed = eg[i + 6 + half];
            uint2 pa = hu[(size_t)ea.x * 32 + cl];
            uint2 pb = hu[(size_t)eb.x * 32 + cl];
            uint2 pc = hu[(size_t)ec.x * 32 + cl];
            uint2 pd = hu[(size_t)ed.x * 32 + cl];
            float wa = __int_as_float(ea.z), wb = __int_as_float(eb.z);
            float wc = __int_as_float(ec.z), wd = __int_as_float(ed.z);
            a0 += wa * lo2f(pa.x) + wb * lo2f(pb.x) + wc * lo2f(pc.x) + wd * lo2f(pd.x);
            a1 += wa * hi2f(pa.x) + wb * hi2f(pb.x) + wc * hi2f(pc.x) + wd * hi2f(pd.x);
            a2 += wa * lo2f(pa.y) + wb * lo2f(pb.y) + wc * lo2f(pc.y) + wd * lo2f(pd.y);
            a3 += wa * hi2f(pa.y) + wb * hi2f(pb.y) + wc * hi2f(pc.y) + wd * hi2f(pd.y);
        }
        for (; i + 3 < e; i += 4) {
            int4 ea = eg[i + half], eb = eg[i + 2 + half];
            uint2 pa = hu[(size_t)ea.x * 32 + cl];
            uint2 pb = hu[(size_t)eb.x * 32 + cl];
            float wa = __int_as_float(ea.z), wb = __int_as_float(eb.z);
            a0 += wa * lo2f(pa.x) + wb * lo2f(pb.x);
            a1 += wa * hi2f(pa.x) + wb * hi2f(pb.x);
            a2 += wa * lo2f(pa.y) + wb * lo2f(pb.y);
            a3 += wa * hi2f(pa.y) + wb * hi2f(pb.y);
        }
        for (; i < e; i += 2) {
            int idx = i + half;
            int4 ee = eg[idx < e ? idx : i];
            float w = (idx < e) ? __int_as_float(ee.z) : 0.0f;
            uint2 p = hu[(size_t)ee.x * 32 + cl];
            a0 += w * lo2f(p.x); a1 += w * hi2f(p.x);
            a2 += w * lo2f(p.y); a3 += w * hi2f(p.y);
        }
        a0 += __shfl_xor(a0, 32); a1 += __shfl_xor(a1, 32);
        a2 += __shfl_xor(a2, 32); a3 += __shfl_xor(a3, 32);
        float sc = scale[n];
        r0 += fmaxf(a0 * sc, 0.0f); r1 += fmaxf(a1 * sc, 0.0f);
        r2 += fmaxf(a2 * sc, 0.0f); r3 += fmaxf(a3 * sc, 0.0f);
    }
    atomicAdd(&ro[cur * OUT_DIM + 4 * cl + 2 * half], half ? r2 : r0);
    atomicAdd(&ro[cur * OUT_DIM + 4 * cl + 2 * half + 1], half ? r3 : r1);
}

// ---------------- MFMA bf16 GEMM core: 128x128 tile, BK=64, swizzled global_load_lds ------

__device__ __forceinline__ void gemm_core(short* As, short* Bs,
    const unsigned short* __restrict__ A, const unsigned short* __restrict__ A2,
    const unsigned short* __restrict__ Bt, unsigned short* __restrict__ C,
    const float* __restrict__ rowScaleC, int K1, int K2, int N,
    int relu, int scaleC, int m0, int n0) {
    int tid = threadIdx.x;
    int lane = tid & 63, wave = tid >> 6;
    int wm = (wave >> 1) * 64, wn = (wave & 1) * 64;
    int quad = lane >> 4, r16 = lane & 15;
    const int K = K1 + K2;
    f32x4 acc[4][4] = {};
    int srow = lane >> 3;                     // 0..7 (row within 8-row DMA group)
    int sk   = ((lane & 7) ^ srow) * 8;       // swizzled source k-chunk (elems)
    int xorc = r16 & 7;
    short* ldsA = As + wave * 2048;           // wave stages rows [wave*32, wave*32+32)
    short* ldsB = Bs + wave * 2048;

    for (int k0 = 0; k0 < K; k0 += 64) {
        int kk = k0 + sk;
#pragma unroll
        for (int h = 0; h < 4; ++h) {
            int r = wave * 32 + h * 8 + srow;
            const unsigned short* Ap = (k0 < K1)
                ? A  + (size_t)(m0 + r) * K1 + kk
                : A2 + (size_t)(m0 + r) * K2 + (kk - K1);
            gll16(Ap, ldsA + h * 512);
            gll16(Bt + (size_t)(n0 + r) * K + kk, ldsB + h * 512);
        }
        __syncthreads();
#pragma unroll
        for (int c = 0; c < 2; ++c) {
            s16x8 af[4], bfr[4];
            int pc = (((c * 4 + quad) ^ xorc) << 3);
#pragma unroll
            for (int i = 0; i < 4; ++i)
                af[i] = *(const s16x8*)(As + (wm + i * 16 + r16) * 64 + pc);
#pragma unroll
            for (int j = 0; j < 4; ++j)
                bfr[j] = *(const s16x8*)(Bs + (wn + j * 16 + r16) * 64 + pc);
#pragma unroll
            for (int i = 0; i < 4; ++i)
#pragma unroll
                for (int j = 0; j < 4; ++j)
                    acc[i][j] = __builtin_amdgcn_mfma_f32_16x16x32_bf16(
                        __builtin_bit_cast(bf16x8, af[i]), __builtin_bit_cast(bf16x8, bfr[j]),
                        acc[i][j], 0, 0, 0);
        }
        __syncthreads();
    }

#pragma unroll
    for (int i = 0; i < 4; ++i) {
        int mbase = m0 + wm + i * 16 + quad * 4;
#pragma unroll
        for (int r = 0; r < 4; ++r) {
            int m = mbase + r;
            float sc = scaleC ? rowScaleC[m] : 1.0f;
#pragma unroll
            for (int j = 0; j < 4; ++j) {
                float v = acc[i][j][r] * sc;
                if (relu) v = fmaxf(v, 0.0f);
                C[(size_t)m * N + n0 + wn + j * 16 + r16] = f2b(v);
            }
        }
    }
}

template <int RELU, int SCALE_C>
__global__ __launch_bounds__(256) void gemm_mfma(
    const unsigned short* __restrict__ A, const unsigned short* __restrict__ A2,
    const unsigned short* __restrict__ Bt, unsigned short* __restrict__ C,
    const float* __restrict__ rowScaleC, int K1, int K2, int N) {
    __shared__ short As[8192];
    __shared__ short Bs[8192];
    gemm_core(As, Bs, A, A2, Bt, C, rowScaleC, K1, K2, N, RELU, SCALE_C,
              blockIdx.x * 128, blockIdx.y * 128);
}

// -------- conv1 GEMM: 128x256 tile, 512 threads, K=128, relu ----

__global__ __launch_bounds__(512) void gemm_conv1(
    const unsigned short* __restrict__ A, const unsigned short* __restrict__ Bt,
    unsigned short* __restrict__ C) {
    __shared__ short As[4096];   // [128][32]
    __shared__ short Bs[8192];   // [256][32]
    int tid = threadIdx.x;
    int lane = tid & 63, wave = tid >> 6;      // 0..7
    int wm = (wave >> 2) * 64, wn = (wave & 3) * 64;
    int quad = lane >> 4, r16 = lane & 15;
    int m0 = blockIdx.x * 128;
    f32x4 acc[4][4] = {};
    int lrow = lane >> 2;
    int kc = (lane & 3) * 8;
    short* ldsA = As + wave * 512;
    short* ldsB = Bs + wave * 512;

    for (int k0 = 0; k0 < 128; k0 += 32) {
        int kk = k0 + kc;
        int rr = wave * 16 + lrow;  // 0..127
        gll16(A + (size_t)(m0 + rr) * 128 + kk, ldsA);
        gll16(Bt + (size_t)rr * 128 + kk, ldsB);
        gll16(Bt + (size_t)(128 + rr) * 128 + kk, ldsB + 4096);
        __syncthreads();
        s16x8 af[4], bfr[4];
#pragma unroll
        for (int i = 0; i < 4; ++i)
            af[i] = *(const s16x8*)(As + (wm + i * 16 + r16) * 32 + quad * 8);
#pragma unroll
        for (int j = 0; j < 4; ++j)
            bfr[j] = *(const s16x8*)(Bs + (wn + j * 16 + r16) * 32 + quad * 8);
#pragma unroll
        for (int i = 0; i < 4; ++i)
#pragma unroll
            for (int j = 0; j < 4; ++j)
                acc[i][j] = __builtin_amdgcn_mfma_f32_16x16x32_bf16(
                    __builtin_bit_cast(bf16x8, af[i]), __builtin_bit_cast(bf16x8, bfr[j]),
                    acc[i][j], 0, 0, 0);
        __syncthreads();
    }

#pragma unroll
    for (int i = 0; i < 4; ++i) {
        int mbase = m0 + wm + i * 16 + quad * 4;
#pragma unroll
        for (int r = 0; r < 4; ++r) {
            int m = mbase + r;
#pragma unroll
            for (int j = 0; j < 4; ++j)
                C[(size_t)m * 256 + wn + j * 16 + r16] = f2b(fmaxf(acc[i][j][r], 0.0f));
        }
    }
}

// ---------------- normalize ----------------

__global__ void normalize_out(const float* __restrict__ ro, float* __restrict__ out) {
    int g = blockIdx.x;
    int d = threadIdx.x;  // 128 threads = 2 waves
    float v = ro[g * OUT_DIM + d];
    float ss = v * v;
#pragma unroll
    for (int m = 1; m < 64; m <<= 1) ss += __shfl_xor(ss, m);
    __shared__ float s2[2];
    if ((d & 63) == 0) s2[d >> 6] = ss;
    __syncthreads();
    float tot = s2[0] + s2[1];
    float norm = fmaxf(sqrtf(tot), 1e-12f);
    out[g * OUT_DIM + d] = v / norm;
}

// ---------------- launch ----------------

extern "C" void kernel_launch(void* const* d_in, const int* in_sizes, int n_in,
                              void* d_out, int out_size, void* d_ws, size_t ws_size,
                              hipStream_t stream) {
    const float* x    = (const float*)d_in[0];
    const float* w    = (const float*)d_in[1];
    const float* W1   = (const float*)d_in[2];
    const float* fc1W = (const float*)d_in[3];
    const float* gam  = (const float*)d_in[4];
    const float* bet  = (const float*)d_in[5];
    const float* W2   = (const float*)d_in[6];
    const float* W3   = (const float*)d_in[7];
    const int* src = (const int*)d_in[8];
    const int* dst = (const int*)d_in[9];
    const int* gid = (const int*)d_in[10];
    float* out = (float*)d_out;

    float* ws = (float*)d_ws;
    float* out_inv = ws + 0;                                 // 40000
    float* in_inv  = ws + 40000;                             // 40000
    float* ew      = ws + 80000;                             // 320000
    int*   cnt_out = (int*)(ws + 400000);                    // 40000 (memset group start)
    int*   cnt_in  = (int*)(ws + 440000);                    // 40000 (memset group)
    float* ro      = ws + 480000;                            // 8192 (memset group end)
    unsigned short* W1t  = (unsigned short*)(ws + 488192);   // [256][128]
    unsigned short* fc1t = (unsigned short*)(ws + 504576);   // [256][128]
    unsigned short* W2t  = (unsigned short*)(ws + 520960);   // [256][512]
    unsigned short* W3t  = (unsigned short*)(ws + 586496);   // [128][256]
    int*   partial = (int*)(ws + 602880);                    // 40
    int*   off     = (int*)(ws + 602920);                    // 40001 ints -> ends 642921
    int4*  es      = (int4*)(ws + 642924);                   // 320000 int4 (16B-aligned)
    unsigned short* xb    = (unsigned short*)(ws + 1923000); // [M_PAD][128] ; later Q3b
    unsigned short* Q3b   = xb;
    unsigned short* agg1b = (unsigned short*)(ws + 4487100); // [M_PAD][128..256] ; later x2b
    unsigned short* x2b   = agg1b;
    unsigned short* x1b   = (unsigned short*)(ws + 9615300); // [M_PAD][256]
    unsigned short* f1b   = (unsigned short*)(ws + 14743500);// [M_PAD][256]
    unsigned short* P2b   = (unsigned short*)(ws + 19871700);// [M_PAD][256]

    // one memset covers cnt_out | cnt_in | ro (contiguous)
    hipMemsetAsync(cnt_out, 0, (2 * 40000 + N_GRAPHS * OUT_DIM) * sizeof(float), stream);

    // fused conversions + edge weights + degree histograms
    prep_all<<<(PREP_TOT + 255) / 256, 256, 0, stream>>>(x, W1, fc1W, W2, W3, w, src, dst,
                                                         xb, W1t, fc1t, W2t, W3t, ew,
                                                         cnt_out, cnt_in);
    scan_part<<<40, 256, 0, stream>>>(cnt_in, partial);
    scan_final<<<40, 1024, 0, stream>>>(cnt_in, cnt_out, partial, off, out_inv, in_inv);

    // fused: csr_fill (625 blocks) + fc1 GEMM+LN (313 blocks) — independent work overlapped
    csr_fc1<<<625 + 313, 512, 0, stream>>>(src, dst, ew, out_inv, off, cnt_in, es,
                                           xb, fc1t, f1b, gam, bet);

    // conv1 gather (8 waves/block, 1 node/wave), then conv1 GEMM
    gather_nodes<IN_DIM, 0, 0><<<5000, 512, 0, stream>>>(xb, off, es, in_inv, agg1b);
    gemm_conv1<<<313, 512, 0, stream>>>(agg1b, W1t, x1b);

    // conv2
    {
        dim3 grid(M_PAD / 128, HID4 / 128);
        gemm_mfma<0, 1><<<grid, 256, 0, stream>>>(x1b, f1b, W2t, P2b, out_inv,
                                                  HID4, HID4, HID4);
    }
    gather_nodes<HID4, 1, 1><<<5000, 512, 0, stream>>>(P2b, off, es, in_inv, x2b);

    // conv3
    {
        dim3 grid(M_PAD / 128, OUT_DIM / 128);
        gemm_mfma<0, 1><<<grid, 256, 0, stream>>>(x2b, nullptr, W3t, Q3b, out_inv,
                                                  HID4, 0, OUT_DIM);
    }
    // conv3 gather fused with readout (x3 never materialized)
    gather3_ro<<<625, 512, 0, stream>>>(Q3b, off, es, in_inv, gid, ro);
    normalize_out<<<N_GRAPHS, 128, 0, stream>>>(ro, out);
}

// Round 4
// 287.758 us; speedup vs baseline: 1.0877x; 1.0138x over previous
//
#include <hip/hip_runtime.h>

#define N_NODES 40000
#define M_PAD   40064   // 313 * 128 = 626 * 64
#define N_EDGES 320000
#define N_GRAPHS 64
#define IN_DIM 128
#define HID4 256
#define OUT_DIM 128
#define LN_EPS 1e-5f

typedef short  s16x8  __attribute__((ext_vector_type(8)));
typedef __bf16 bf16x8 __attribute__((ext_vector_type(8)));
typedef float  f32x4  __attribute__((ext_vector_type(4)));

__device__ __forceinline__ unsigned short f2b(float f) {
    unsigned int u = __builtin_bit_cast(unsigned int, f);
    u += 0x7fffu + ((u >> 16) & 1u);   // round-to-nearest-even
    return (unsigned short)(u >> 16);
}
__device__ __forceinline__ float b2f(unsigned short h) {
    unsigned int u = (unsigned int)h << 16;
    return __builtin_bit_cast(float, u);
}
__device__ __forceinline__ float lo2f(unsigned int u) { return b2f((unsigned short)u); }
__device__ __forceinline__ float hi2f(unsigned int u) { return b2f((unsigned short)(u >> 16)); }
__device__ __forceinline__ unsigned int packb(float x, float y) {
    return (unsigned int)f2b(x) | ((unsigned int)f2b(y) << 16);
}

// direct global->LDS 16B DMA; lds base wave-uniform, HW scatters lane*16
__device__ __forceinline__ void gll16(const unsigned short* g, short* lds_base) {
    __builtin_amdgcn_global_load_lds(
        (const __attribute__((address_space(1))) unsigned int*)g,
        (__attribute__((address_space(3))) unsigned int*)lds_base, 16, 0, 0);
}

#define MFMA_BF16(a, b, c) __builtin_amdgcn_mfma_f32_16x16x32_bf16( \
    __builtin_bit_cast(bf16x8, a), __builtin_bit_cast(bf16x8, b), c, 0, 0, 0)

// ---------------- fused prep: x->bf16 (vectorized), weights->bf16 transposed, edges ----

#define XN (N_NODES * IN_DIM)          // 5,120,000
#define XT (XN / 8)                    // 640,000 threads, 8 elems each
#define WN 229376                      // 32768*3 + 131072
#define PREP_TOT (XT + WN + N_EDGES)

__global__ void prep_all(const float* __restrict__ x, const float* __restrict__ W1,
                         const float* __restrict__ fc1, const float* __restrict__ W2,
                         const float* __restrict__ W3, const float* __restrict__ w,
                         const int* __restrict__ src, const int* __restrict__ dst,
                         unsigned short* __restrict__ xb, unsigned short* __restrict__ W1t,
                         unsigned short* __restrict__ fc1t, unsigned short* __restrict__ W2t,
                         unsigned short* __restrict__ W3t, float* __restrict__ ew,
                         int* __restrict__ cnt_out, int* __restrict__ cnt_in) {
    int idx = blockIdx.x * 256 + threadIdx.x;
    if (idx < XT) {
        const float4* xv = (const float4*)x;
        float4 u = xv[idx * 2], v = xv[idx * 2 + 1];
        uint4 o;
        o.x = packb(u.x, u.y); o.y = packb(u.z, u.w);
        o.z = packb(v.x, v.y); o.w = packb(v.z, v.w);
        ((uint4*)xb)[idx] = o;
        return;
    }
    int j = idx - XT;
    if (j < 32768) { int k = j >> 8, n = j & 255; W1t[n * 128 + k] = f2b(W1[j]); return; }
    j -= 32768;
    if (j < 32768) { int k = j >> 8, n = j & 255; fc1t[n * 128 + k] = f2b(fc1[j]); return; }
    j -= 32768;
    if (j < 131072) { int k = j >> 8, n = j & 255; W2t[n * 512 + k] = f2b(W2[j]); return; }
    j -= 131072;
    if (j < 32768) { int k = j >> 7, n = j & 127; W3t[n * 256 + k] = f2b(W3[j]); return; }
    j -= 32768;
    if (j < N_EDGES) {
        float4 v = ((const float4*)w)[j];
        ew[j] = fmaxf(fmaxf(v.x, v.y), fmaxf(v.z, v.w));
        atomicAdd(&cnt_out[src[j]], 1);
        atomicAdd(&cnt_in[dst[j]], 1);
    }
}

// stage 1: 40 blocks x 256 threads, block b sums cnt[b*1000 .. b*1000+999]
__global__ void scan_part(const int* __restrict__ cnt, int* __restrict__ partial) {
    int b = blockIdx.x;
    int s = 0;
    for (int i = threadIdx.x; i < 1000; i += 256) s += cnt[b * 1000 + i];
#pragma unroll
    for (int m = 1; m < 64; m <<= 1) s += __shfl_xor(s, m);
    __shared__ int wsm[4];
    if ((threadIdx.x & 63) == 0) wsm[threadIdx.x >> 6] = s;
    __syncthreads();
    if (threadIdx.x == 0) partial[b] = wsm[0] + wsm[1] + wsm[2] + wsm[3];
}

// stage 2: 40 blocks x 1024 threads; exclusive scan -> off ; also inv-sqrt degrees
__global__ void scan_final(const int* __restrict__ cnt_in, const int* __restrict__ cnt_out,
                           const int* __restrict__ partial, int* __restrict__ off,
                           float* __restrict__ out_inv, float* __restrict__ in_inv) {
    int b = blockIdx.x, tid = threadIdx.x;
    int lane = tid & 63, wv = tid >> 6;
    int pre = 0;
    for (int j = 0; j < b; ++j) pre += partial[j];
    int i = b * 1000 + tid;
    int v = (tid < 1000) ? cnt_in[i] : 0;
    int x = v;
#pragma unroll
    for (int ofs = 1; ofs < 64; ofs <<= 1) {
        int t = __shfl_up(x, ofs);
        if (lane >= ofs) x += t;
    }
    __shared__ int wsum[16];
    if (lane == 63) wsum[wv] = x;
    __syncthreads();
    if (wv == 0 && lane < 16) {
        int s = wsum[lane];
#pragma unroll
        for (int ofs = 1; ofs < 16; ofs <<= 1) {
            int t = __shfl_up(s, ofs);
            if (lane >= ofs) s += t;
        }
        wsum[lane] = s;
    }
    __syncthreads();
    int incl = pre + (wv > 0 ? wsum[wv - 1] : 0) + x;
    if (tid < 1000) {
        off[i] = incl - v;   // exclusive
        in_inv[i] = rsqrtf(fmaxf((float)v, 1.0f));
        out_inv[i] = rsqrtf(fmaxf((float)cnt_out[i], 1.0f));
    }
    if (b == 39 && tid == 999) off[N_NODES] = incl;
}

// ---- fused csr_fill + fc1 GEMM(+LN) hetero launch: blocks [0,625) csr, [625,938) fc1 ----

__global__ __launch_bounds__(512) void csr_fc1(
    const int* __restrict__ src, const int* __restrict__ dst,
    const float* __restrict__ ew, const float* __restrict__ out_inv,
    const int* __restrict__ off, int* __restrict__ cnt_in, int4* __restrict__ es,
    const unsigned short* __restrict__ A, const unsigned short* __restrict__ Bt,
    unsigned short* __restrict__ C,
    const float* __restrict__ gamma, const float* __restrict__ beta) {
    __shared__ short As[4096];   // [128][32]
    __shared__ short Bs[8192];   // [256][32]
    __shared__ float lns[128][4];
    __shared__ float lnq[128][4];
    if (blockIdx.x < 625) {
        int e = blockIdx.x * 512 + threadIdx.x;
        if (e >= N_EDGES) return;
        int d = dst[e];
        int slot = off[d] + atomicSub(&cnt_in[d], 1) - 1;
        int s = src[e];
        float wv = ew[e];
        es[slot] = make_int4(s, __float_as_int(wv * out_inv[s]), __float_as_int(wv), 0);
        return;
    }
    int m0 = (blockIdx.x - 625) * 128;
    int tid = threadIdx.x;
    int lane = tid & 63, wave = tid >> 6;      // 0..7
    int wm = (wave >> 2) * 64, wn = (wave & 3) * 64;
    int quad = lane >> 4, r16 = lane & 15;
    f32x4 acc[4][4] = {};
    int lrow = lane >> 2;
    int kc = (lane & 3) * 8;
    short* ldsA = As + wave * 512;
    short* ldsB = Bs + wave * 512;

    for (int k0 = 0; k0 < 128; k0 += 32) {
        int kk = k0 + kc;
        int rr = wave * 16 + lrow;  // 0..127
        gll16(A + (size_t)(m0 + rr) * 128 + kk, ldsA);
        gll16(Bt + (size_t)rr * 128 + kk, ldsB);
        gll16(Bt + (size_t)(128 + rr) * 128 + kk, ldsB + 4096);
        __syncthreads();
        s16x8 af[4], bfr[4];
#pragma unroll
        for (int i = 0; i < 4; ++i)
            af[i] = *(const s16x8*)(As + (wm + i * 16 + r16) * 32 + quad * 8);
#pragma unroll
        for (int j = 0; j < 4; ++j)
            bfr[j] = *(const s16x8*)(Bs + (wn + j * 16 + r16) * 32 + quad * 8);
#pragma unroll
        for (int i = 0; i < 4; ++i)
#pragma unroll
            for (int j = 0; j < 4; ++j)
                acc[i][j] = MFMA_BF16(af[i], bfr[j], acc[i][j]);
        __syncthreads();
    }

    // LayerNorm(affine) + relu from fp32 accumulators
#pragma unroll
    for (int i = 0; i < 4; ++i)
#pragma unroll
        for (int r = 0; r < 4; ++r) {
            float s = 0.0f, q = 0.0f;
#pragma unroll
            for (int j = 0; j < 4; ++j) { float v = acc[i][j][r]; s += v; q += v * v; }
#pragma unroll
            for (int m = 1; m < 16; m <<= 1) { s += __shfl_xor(s, m); q += __shfl_xor(q, m); }
            if (r16 == 0) {
                int row = wm + i * 16 + quad * 4 + r;
                lns[row][wave & 3] = s;
                lnq[row][wave & 3] = q;
            }
        }
    __syncthreads();
#pragma unroll
    for (int i = 0; i < 4; ++i) {
#pragma unroll
        for (int r = 0; r < 4; ++r) {
            int row = wm + i * 16 + quad * 4 + r;
            float s = lns[row][0] + lns[row][1] + lns[row][2] + lns[row][3];
            float q = lnq[row][0] + lnq[row][1] + lnq[row][2] + lnq[row][3];
            float mu = s * (1.0f / HID4);
            float var = q * (1.0f / HID4) - mu * mu;
            float rs = rsqrtf(var + LN_EPS);
            int m = m0 + row;
#pragma unroll
            for (int j = 0; j < 4; ++j) {
                int col = wn + j * 16 + r16;
                float v = (acc[i][j][r] - mu) * rs * gamma[col] + beta[col];
                C[(size_t)m * 256 + col] = f2b(fmaxf(v, 0.0f));
            }
        }
    }
}

// ---------------- gather accumulation inner loops (half-split, 4-deep MLP) ----------------

template <int WSEL>
__device__ __forceinline__ void gacc128(int b, int e, int half, int cl,
        const uint2* __restrict__ hu, const int4* __restrict__ eg,
        float& a0, float& a1, float& a2, float& a3) {
    int i = b;
    for (; i + 7 < e; i += 8) {
        int4 ea = eg[i + half],     eb = eg[i + 2 + half];
        int4 ec = eg[i + 4 + half], ed = eg[i + 6 + half];
        uint2 pa = hu[(size_t)ea.x * 32 + cl];
        uint2 pb = hu[(size_t)eb.x * 32 + cl];
        uint2 pc = hu[(size_t)ec.x * 32 + cl];
        uint2 pd = hu[(size_t)ed.x * 32 + cl];
        float wa = __int_as_float(WSEL ? ea.z : ea.y);
        float wb = __int_as_float(WSEL ? eb.z : eb.y);
        float wc = __int_as_float(WSEL ? ec.z : ec.y);
        float wd = __int_as_float(WSEL ? ed.z : ed.y);
        a0 += wa * lo2f(pa.x) + wb * lo2f(pb.x) + wc * lo2f(pc.x) + wd * lo2f(pd.x);
        a1 += wa * hi2f(pa.x) + wb * hi2f(pb.x) + wc * hi2f(pc.x) + wd * hi2f(pd.x);
        a2 += wa * lo2f(pa.y) + wb * lo2f(pb.y) + wc * lo2f(pc.y) + wd * lo2f(pd.y);
        a3 += wa * hi2f(pa.y) + wb * hi2f(pb.y) + wc * hi2f(pc.y) + wd * hi2f(pd.y);
    }
    for (; i + 3 < e; i += 4) {
        int4 ea = eg[i + half], eb = eg[i + 2 + half];
        uint2 pa = hu[(size_t)ea.x * 32 + cl];
        uint2 pb = hu[(size_t)eb.x * 32 + cl];
        float wa = __int_as_float(WSEL ? ea.z : ea.y);
        float wb = __int_as_float(WSEL ? eb.z : eb.y);
        a0 += wa * lo2f(pa.x) + wb * lo2f(pb.x);
        a1 += wa * hi2f(pa.x) + wb * hi2f(pb.x);
        a2 += wa * lo2f(pa.y) + wb * lo2f(pb.y);
        a3 += wa * hi2f(pa.y) + wb * hi2f(pb.y);
    }
    for (; i < e; i += 2) {
        int idx = i + half;
        int4 ee = eg[idx < e ? idx : i];
        float w = (idx < e) ? __int_as_float(WSEL ? ee.z : ee.y) : 0.0f;
        uint2 p = hu[(size_t)ee.x * 32 + cl];
        a0 += w * lo2f(p.x); a1 += w * hi2f(p.x);
        a2 += w * lo2f(p.y); a3 += w * hi2f(p.y);
    }
}

template <int WSEL>
__device__ __forceinline__ void gacc256(int b, int e, int half, int cl,
        const uint4* __restrict__ hu, const int4* __restrict__ eg,
        float& a0, float& a1, float& a2, float& a3,
        float& a4, float& a5, float& a6, float& a7) {
    int i = b;
    for (; i + 7 < e; i += 8) {
        int4 ea = eg[i + half],     eb = eg[i + 2 + half];
        int4 ec = eg[i + 4 + half], ed = eg[i + 6 + half];
        uint4 pa = hu[(size_t)ea.x * 32 + cl];
        uint4 pb = hu[(size_t)eb.x * 32 + cl];
        uint4 pc = hu[(size_t)ec.x * 32 + cl];
        uint4 pd = hu[(size_t)ed.x * 32 + cl];
        float wa = __int_as_float(WSEL ? ea.z : ea.y);
        float wb = __int_as_float(WSEL ? eb.z : eb.y);
        float wc = __int_as_float(WSEL ? ec.z : ec.y);
        float wd = __int_as_float(WSEL ? ed.z : ed.y);
        a0 += wa * lo2f(pa.x) + wb * lo2f(pb.x) + wc * lo2f(pc.x) + wd * lo2f(pd.x);
        a1 += wa * hi2f(pa.x) + wb * hi2f(pb.x) + wc * hi2f(pc.x) + wd * hi2f(pd.x);
        a2 += wa * lo2f(pa.y) + wb * lo2f(pb.y) + wc * lo2f(pc.y) + wd * lo2f(pd.y);
        a3 += wa * hi2f(pa.y) + wb * hi2f(pb.y) + wc * hi2f(pc.y) + wd * hi2f(pd.y);
        a4 += wa * lo2f(pa.z) + wb * lo2f(pb.z) + wc * lo2f(pc.z) + wd * lo2f(pd.z);
        a5 += wa * hi2f(pa.z) + wb * hi2f(pb.z) + wc * hi2f(pc.z) + wd * hi2f(pd.z);
        a6 += wa * lo2f(pa.w) + wb * lo2f(pb.w) + wc * lo2f(pc.w) + wd * lo2f(pd.w);
        a7 += wa * hi2f(pa.w) + wb * hi2f(pb.w) + wc * hi2f(pc.w) + wd * hi2f(pd.w);
    }
    for (; i + 3 < e; i += 4) {
        int4 ea = eg[i + half], eb = eg[i + 2 + half];
        uint4 pa = hu[(size_t)ea.x * 32 + cl];
        uint4 pb = hu[(size_t)eb.x * 32 + cl];
        float wa = __int_as_float(WSEL ? ea.z : ea.y);
        float wb = __int_as_float(WSEL ? eb.z : eb.y);
        a0 += wa * lo2f(pa.x) + wb * lo2f(pb.x); a1 += wa * hi2f(pa.x) + wb * hi2f(pb.x);
        a2 += wa * lo2f(pa.y) + wb * lo2f(pb.y); a3 += wa * hi2f(pa.y) + wb * hi2f(pb.y);
        a4 += wa * lo2f(pa.z) + wb * lo2f(pb.z); a5 += wa * hi2f(pa.z) + wb * hi2f(pb.z);
        a6 += wa * lo2f(pa.w) + wb * lo2f(pb.w); a7 += wa * hi2f(pa.w) + wb * hi2f(pb.w);
    }
    for (; i < e; i += 2) {
        int idx = i + half;
        int4 ee = eg[idx < e ? idx : i];
        float w = (idx < e) ? __int_as_float(WSEL ? ee.z : ee.y) : 0.0f;
        uint4 p = hu[(size_t)ee.x * 32 + cl];
        a0 += w * lo2f(p.x); a1 += w * hi2f(p.x);
        a2 += w * lo2f(p.y); a3 += w * hi2f(p.y);
        a4 += w * lo2f(p.z); a5 += w * hi2f(p.z);
        a6 += w * lo2f(p.w); a7 += w * hi2f(p.w);
    }
}

// ---- fused gather1 + conv1 + conv2: block owns 64 rows; agg1/x1 never hit global ----
// LDS: T1s[64][264] (33792B, first 17408B doubles as Ag[64][136]) + Bs[256][64] (32768B)
// = 66.5 KB -> 2 blocks/CU. Strides 136/264 shorts = 68/132 words == 4 (mod 32) -> 2-way
// banks on ds_read_b128 (free). Bs uses gemm_core's swizzled-source global_load_lds.

__global__ __launch_bounds__(512, 4) void fused_g1c12(
    const unsigned short* __restrict__ xb, const int* __restrict__ off,
    const int4* __restrict__ es, const float* __restrict__ in_inv,
    const unsigned short* __restrict__ W1t, const unsigned short* __restrict__ f1b,
    const unsigned short* __restrict__ W2t, const float* __restrict__ out_inv,
    unsigned short* __restrict__ P2b) {
    __shared__ short T1s[64 * 264];
    __shared__ short Bs[256 * 64];
    int tid = threadIdx.x, lane = tid & 63, wave = tid >> 6;   // 8 waves
    int half = lane >> 5, cl = lane & 31;
    int m0 = blockIdx.x * 64;
    short* Ag = T1s;   // [64][136] overlay, dead after GEMM1

    // phase 1: gather agg1 rows (in_inv-scaled) into Ag
    const uint2* hu = (const uint2*)xb;
    for (int t = 0; t < 8; ++t) {
        int row = wave * 8 + t;
        int n = m0 + row;
        float a0 = 0.f, a1 = 0.f, a2 = 0.f, a3 = 0.f;
        if (n < N_NODES)
            gacc128<0>(off[n], off[n + 1], half, cl, hu, es, a0, a1, a2, a3);
        a0 += __shfl_xor(a0, 32); a1 += __shfl_xor(a1, 32);
        a2 += __shfl_xor(a2, 32); a3 += __shfl_xor(a3, 32);
        if (n < N_NODES) {
            float sc = in_inv[n];
            a0 *= sc; a1 *= sc; a2 *= sc; a3 *= sc;
        }
        if (half == 0) {
            uint2 o; o.x = packb(a0, a1); o.y = packb(a2, a3);
            *(uint2*)(Ag + row * 136 + cl * 4) = o;
        }
    }
    __syncthreads();

    int srow = lane >> 3, sk = ((lane & 7) ^ srow) * 8;
    int quad = lane >> 4, r16 = lane & 15, xorc = r16 & 7;
    int wm = (wave >> 2) * 32, wn = (wave & 3) * 64;

    // phase 2: GEMM1  T1 = relu(Ag @ W1t^T), K=128
    f32x4 acc[2][4] = {};
    for (int k0 = 0; k0 < 128; k0 += 64) {
#pragma unroll
        for (int h = 0; h < 4; ++h)
            gll16(W1t + (wave * 32 + h * 8 + srow) * 128 + k0 + sk,
                  Bs + wave * 2048 + h * 512);
        __syncthreads();
#pragma unroll
        for (int c = 0; c < 2; ++c) {
            int pcB = (((c * 4 + quad) ^ xorc) << 3);
            int colA = k0 + (c * 4 + quad) * 8;
            s16x8 af[2], bfr[4];
#pragma unroll
            for (int i = 0; i < 2; ++i)
                af[i] = *(const s16x8*)(Ag + (wm + i * 16 + r16) * 136 + colA);
#pragma unroll
            for (int j = 0; j < 4; ++j)
                bfr[j] = *(const s16x8*)(Bs + (wn + j * 16 + r16) * 64 + pcB);
#pragma unroll
            for (int i = 0; i < 2; ++i)
#pragma unroll
                for (int j = 0; j < 4; ++j)
                    acc[i][j] = MFMA_BF16(af[i], bfr[j], acc[i][j]);
        }
        __syncthreads();
    }

    // phase 3: T1 (relu, bf16) -> T1s[64][264], overwriting Ag
#pragma unroll
    for (int i = 0; i < 2; ++i)
#pragma unroll
        for (int r = 0; r < 4; ++r) {
            int row = wm + i * 16 + quad * 4 + r;
#pragma unroll
            for (int j = 0; j < 4; ++j)
                T1s[row * 264 + wn + j * 16 + r16] =
                    (short)f2b(fmaxf(acc[i][j][r], 0.0f));
        }
    __syncthreads();

    // phase 4: GEMM2  P2 = [T1 | f1] @ W2t^T, K=512 (T1 from LDS, f1 streamed global)
    f32x4 acc2[2][4] = {};
    for (int k0 = 0; k0 < 512; k0 += 64) {
#pragma unroll
        for (int h = 0; h < 4; ++h)
            gll16(W2t + (size_t)(wave * 32 + h * 8 + srow) * 512 + k0 + sk,
                  Bs + wave * 2048 + h * 512);
        s16x8 afg[2][2];
        if (k0 >= 256) {
#pragma unroll
            for (int i = 0; i < 2; ++i)
#pragma unroll
                for (int c = 0; c < 2; ++c)
                    afg[i][c] = *(const s16x8*)(f1b +
                        (size_t)(m0 + wm + i * 16 + r16) * 256 +
                        (k0 - 256) + (c * 4 + quad) * 8);
        }
        __syncthreads();
#pragma unroll
        for (int c = 0; c < 2; ++c) {
            int pcB = (((c * 4 + quad) ^ xorc) << 3);
            int colA = k0 + (c * 4 + quad) * 8;
            s16x8 af[2], bfr[4];
#pragma unroll
            for (int i = 0; i < 2; ++i)
                af[i] = (k0 < 256)
                    ? *(const s16x8*)(T1s + (wm + i * 16 + r16) * 264 + colA)
                    : afg[i][c];
#pragma unroll
            for (int j = 0; j < 4; ++j)
                bfr[j] = *(const s16x8*)(Bs + (wn + j * 16 + r16) * 64 + pcB);
#pragma unroll
            for (int i = 0; i < 2; ++i)
#pragma unroll
                for (int j = 0; j < 4; ++j)
                    acc2[i][j] = MFMA_BF16(af[i], bfr[j], acc2[i][j]);
        }
        __syncthreads();
    }

    // epilogue: P2b = acc2 * out_inv[row]  (no relu)
#pragma unroll
    for (int i = 0; i < 2; ++i)
#pragma unroll
        for (int r = 0; r < 4; ++r) {
            int m = m0 + wm + i * 16 + quad * 4 + r;
            float sc = out_inv[m];
#pragma unroll
            for (int j = 0; j < 4; ++j)
                P2b[(size_t)m * 256 + wn + j * 16 + r16] = f2b(acc2[i][j][r] * sc);
        }
}

// ---- fused gather2 + conv3: block owns 64 rows; x2 never hits global ----
// LDS: Ag2[64][264] (33792B) + Bs[128][64] (16384B) = 50 KB.

__global__ __launch_bounds__(512, 4) void fused_g2c3(
    const unsigned short* __restrict__ P2b, const int* __restrict__ off,
    const int4* __restrict__ es, const float* __restrict__ in_inv,
    const unsigned short* __restrict__ W3t, const float* __restrict__ out_inv,
    unsigned short* __restrict__ Q3b) {
    __shared__ short Ag2[64 * 264];
    __shared__ short Bs[128 * 64];
    int tid = threadIdx.x, lane = tid & 63, wave = tid >> 6;   // 8 waves
    int half = lane >> 5, cl = lane & 31;
    int m0 = blockIdx.x * 64;

    // phase 1: gather x2 rows (relu(in_inv * agg(ew * P2b[src]))) into Ag2
    const uint4* hu = (const uint4*)P2b;
    for (int t = 0; t < 8; ++t) {
        int row = wave * 8 + t;
        int n = m0 + row;
        float a0 = 0.f, a1 = 0.f, a2 = 0.f, a3 = 0.f;
        float a4 = 0.f, a5 = 0.f, a6 = 0.f, a7 = 0.f;
        if (n < N_NODES)
            gacc256<1>(off[n], off[n + 1], half, cl, hu, es,
                       a0, a1, a2, a3, a4, a5, a6, a7);
        a0 += __shfl_xor(a0, 32); a1 += __shfl_xor(a1, 32);
        a2 += __shfl_xor(a2, 32); a3 += __shfl_xor(a3, 32);
        a4 += __shfl_xor(a4, 32); a5 += __shfl_xor(a5, 32);
        a6 += __shfl_xor(a6, 32); a7 += __shfl_xor(a7, 32);
        if (n < N_NODES) {
            float sc = in_inv[n];
            a0 = fmaxf(a0 * sc, 0.f); a1 = fmaxf(a1 * sc, 0.f);
            a2 = fmaxf(a2 * sc, 0.f); a3 = fmaxf(a3 * sc, 0.f);
            a4 = fmaxf(a4 * sc, 0.f); a5 = fmaxf(a5 * sc, 0.f);
            a6 = fmaxf(a6 * sc, 0.f); a7 = fmaxf(a7 * sc, 0.f);
        }
        if (half == 0) {
            uint4 o;
            o.x = packb(a0, a1); o.y = packb(a2, a3);
            o.z = packb(a4, a5); o.w = packb(a6, a7);
            *(uint4*)(Ag2 + row * 264 + cl * 8) = o;
        }
    }
    __syncthreads();

    int srow = lane >> 3, sk = ((lane & 7) ^ srow) * 8;
    int quad = lane >> 4, r16 = lane & 15, xorc = r16 & 7;
    int wm = (wave >> 2) * 32, wn = (wave & 3) * 32;

    // phase 2: GEMM  Q3 = (Ag2 @ W3t^T) * out_inv, K=256, N=128
    f32x4 acc[2][2] = {};
    for (int k0 = 0; k0 < 256; k0 += 64) {
#pragma unroll
        for (int h = 0; h < 2; ++h)
            gll16(W3t + (wave * 16 + h * 8 + srow) * 256 + k0 + sk,
                  Bs + wave * 1024 + h * 512);
        __syncthreads();
#pragma unroll
        for (int c = 0; c < 2; ++c) {
            int pcB = (((c * 4 + quad) ^ xorc) << 3);
            int colA = k0 + (c * 4 + quad) * 8;
            s16x8 af[2], bfr[2];
#pragma unroll
            for (int i = 0; i < 2; ++i)
                af[i] = *(const s16x8*)(Ag2 + (wm + i * 16 + r16) * 264 + colA);
#pragma unroll
            for (int j = 0; j < 2; ++j)
                bfr[j] = *(const s16x8*)(Bs + (wn + j * 16 + r16) * 64 + pcB);
#pragma unroll
            for (int i = 0; i < 2; ++i)
#pragma unroll
                for (int j = 0; j < 2; ++j)
                    acc[i][j] = MFMA_BF16(af[i], bfr[j], acc[i][j]);
        }
        __syncthreads();
    }

#pragma unroll
    for (int i = 0; i < 2; ++i)
#pragma unroll
        for (int r = 0; r < 4; ++r) {
            int m = m0 + wm + i * 16 + quad * 4 + r;
            float sc = out_inv[m];
#pragma unroll
            for (int j = 0; j < 2; ++j)
                Q3b[(size_t)m * 128 + wn + j * 16 + r16] = f2b(acc[i][j][r] * sc);
        }
}

// ---------------- gather conv3 + fused readout (8 waves/block, 8-node run per wave) ------

#define G3_NPB 8

__global__ __launch_bounds__(512) void gather3_ro(
        const unsigned short* __restrict__ h, const int* __restrict__ off,
        const int4* __restrict__ eg, const float* __restrict__ scale,
        const int* __restrict__ gid, float* __restrict__ ro) {
    int wave = threadIdx.x >> 6, lane = threadIdx.x & 63;
    int half = lane >> 5, cl = lane & 31;   // lane covers cols 4cl..4cl+3 (half-split edges)
    int n0 = (blockIdx.x * 8 + wave) * G3_NPB;
    if (n0 >= N_NODES) return;
    int n1 = n0 + G3_NPB;
    if (n1 > N_NODES) n1 = N_NODES;
    const uint2* hu = (const uint2*)h;   // row stride 32 (128 bf16)
    float r0 = 0.f, r1 = 0.f, r2 = 0.f, r3 = 0.f;
    int cur = gid[n0];
    for (int n = n0; n < n1; ++n) {
        int g = gid[n];
        if (g != cur) {
            atomicAdd(&ro[cur * OUT_DIM + 4 * cl + 2 * half], half ? r2 : r0);
            atomicAdd(&ro[cur * OUT_DIM + 4 * cl + 2 * half + 1], half ? r3 : r1);
            r0 = r1 = r2 = r3 = 0.f;
            cur = g;
        }
        float a0 = 0.f, a1 = 0.f, a2 = 0.f, a3 = 0.f;
        gacc128<1>(off[n], off[n + 1], half, cl, hu, eg, a0, a1, a2, a3);
        a0 += __shfl_xor(a0, 32); a1 += __shfl_xor(a1, 32);
        a2 += __shfl_xor(a2, 32); a3 += __shfl_xor(a3, 32);
        float sc = scale[n];
        r0 += fmaxf(a0 * sc, 0.0f); r1 += fmaxf(a1 * sc, 0.0f);
        r2 += fmaxf(a2 * sc, 0.0f); r3 += fmaxf(a3 * sc, 0.0f);
    }
    atomicAdd(&ro[cur * OUT_DIM + 4 * cl + 2 * half], half ? r2 : r0);
    atomicAdd(&ro[cur * OUT_DIM + 4 * cl + 2 * half + 1], half ? r3 : r1);
}

// ---------------- normalize ----------------

__global__ void normalize_out(const float* __restrict__ ro, float* __restrict__ out) {
    int g = blockIdx.x;
    int d = threadIdx.x;  // 128 threads = 2 waves
    float v = ro[g * OUT_DIM + d];
    float ss = v * v;
#pragma unroll
    for (int m = 1; m < 64; m <<= 1) ss += __shfl_xor(ss, m);
    __shared__ float s2[2];
    if ((d & 63) == 0) s2[d >> 6] = ss;
    __syncthreads();
    float tot = s2[0] + s2[1];
    float norm = fmaxf(sqrtf(tot), 1e-12f);
    out[g * OUT_DIM + d] = v / norm;
}

// ---------------- launch ----------------

extern "C" void kernel_launch(void* const* d_in, const int* in_sizes, int n_in,
                              void* d_out, int out_size, void* d_ws, size_t ws_size,
                              hipStream_t stream) {
    const float* x    = (const float*)d_in[0];
    const float* w    = (const float*)d_in[1];
    const float* W1   = (const float*)d_in[2];
    const float* fc1W = (const float*)d_in[3];
    const float* gam  = (const float*)d_in[4];
    const float* bet  = (const float*)d_in[5];
    const float* W2   = (const float*)d_in[6];
    const float* W3   = (const float*)d_in[7];
    const int* src = (const int*)d_in[8];
    const int* dst = (const int*)d_in[9];
    const int* gid = (const int*)d_in[10];
    float* out = (float*)d_out;

    float* ws = (float*)d_ws;
    float* out_inv = ws + 0;                                 // 40000
    float* in_inv  = ws + 40000;                             // 40000
    float* ew      = ws + 80000;                             // 320000
    int*   cnt_out = (int*)(ws + 400000);                    // 40000 (memset group start)
    int*   cnt_in  = (int*)(ws + 440000);                    // 40000 (memset group)
    float* ro      = ws + 480000;                            // 8192 (memset group end)
    unsigned short* W1t  = (unsigned short*)(ws + 488192);   // [256][128]
    unsigned short* fc1t = (unsigned short*)(ws + 504576);   // [256][128]
    unsigned short* W2t  = (unsigned short*)(ws + 520960);   // [256][512]
    unsigned short* W3t  = (unsigned short*)(ws + 586496);   // [128][256]
    int*   partial = (int*)(ws + 602880);                    // 40
    int*   off     = (int*)(ws + 602920);                    // 40001 ints
    int4*  es      = (int4*)(ws + 642924);                   // 320000 int4 (16B-aligned)
    unsigned short* xb    = (unsigned short*)(ws + 1923000); // [M_PAD][128] ; later Q3b
    unsigned short* Q3b   = xb;
    unsigned short* f1b   = (unsigned short*)(ws + 14743500);// [M_PAD][256]
    unsigned short* P2b   = (unsigned short*)(ws + 19871700);// [M_PAD][256]

    // one memset covers cnt_out | cnt_in | ro (contiguous)
    hipMemsetAsync(cnt_out, 0, (2 * 40000 + N_GRAPHS * OUT_DIM) * sizeof(float), stream);

    // fused conversions + edge weights + degree histograms
    prep_all<<<(PREP_TOT + 255) / 256, 256, 0, stream>>>(x, W1, fc1W, W2, W3, w, src, dst,
                                                         xb, W1t, fc1t, W2t, W3t, ew,
                                                         cnt_out, cnt_in);
    scan_part<<<40, 256, 0, stream>>>(cnt_in, partial);
    scan_final<<<40, 1024, 0, stream>>>(cnt_in, cnt_out, partial, off, out_inv, in_inv);

    // fused: csr_fill (625 blocks) + fc1 GEMM+LN (313 blocks)
    csr_fc1<<<625 + 313, 512, 0, stream>>>(src, dst, ew, out_inv, off, cnt_in, es,
                                           xb, fc1t, f1b, gam, bet);

    // gather1 + conv1 + conv2 fused (agg1, x1 never materialized)
    fused_g1c12<<<M_PAD / 64, 512, 0, stream>>>(xb, off, es, in_inv, W1t, f1b, W2t,
                                                out_inv, P2b);

    // gather2 + conv3 fused (x2 never materialized)
    fused_g2c3<<<M_PAD / 64, 512, 0, stream>>>(P2b, off, es, in_inv, W3t, out_inv, Q3b);

    // conv3 gather fused with readout (x3 never materialized)
    gather3_ro<<<625, 512, 0, stream>>>(Q3b, off, es, in_inv, gid, ro);
    normalize_out<<<N_GRAPHS, 128, 0, stream>>>(ro, out);
}